// Round 7
// baseline (3276.693 us; speedup 1.0000x reference)
//
#include <hip/hip_runtime.h>
#include <hip/hip_bf16.h>

#define NN 20000
#define NE 320000
#define TOUT 12
#define DEGMAX 96

typedef __bf16 bf16x8 __attribute__((ext_vector_type(8)));
typedef float float4v __attribute__((ext_vector_type(4)));

#define LD8(p) (*(const bf16x8*)(p))
#define MFMA16(a,b,c) __builtin_amdgcn_mfma_f32_16x16x32_bf16((a),(b),(c),0,0,0)

__device__ __forceinline__ float bf2f(const __hip_bfloat16 v){ return __bfloat162float(v); }
__device__ __forceinline__ __hip_bfloat16 f2bf(float v){ return __float2bfloat16(v); }
__device__ __forceinline__ float sigmoidf_(float x){ return 1.0f/(1.0f + __expf(-x)); }
__device__ __forceinline__ float rdf(const void* p, int i, int f32){
  return f32 ? ((const float*)p)[i] : __bfloat162float(((const __hip_bfloat16*)p)[i]);
}

// ---------------- input dtype detector ----------------
__global__ void k_detect(const void* xraw, int* flag){
  __shared__ int cnt;
  if(threadIdx.x == 0) cnt = 0;
  __syncthreads();
  const unsigned* w = (const unsigned*)xraw;
  int local = 0;
  for(int i = threadIdx.x; i < 4096; i += 256){
    unsigned b = (w[i] >> 8) & 0x7F;
    if(b >= 0x33 && b <= 0x3F) local++;
  }
  atomicAdd(&cnt, local);
  __syncthreads();
  if(threadIdx.x == 0) *flag = (cnt > 2048) ? 0 : 1;   // 1 => fp32 inputs
}

// guard signature: constant 256.0 everywhere (fp32 out)
__global__ void k_fail(float* out, int n){
  int i = blockIdx.x*256 + threadIdx.x;
  if(i < n) out[i] = 256.0f;
}

// ---------------- CSR build ----------------
__global__ void k_count(const int* __restrict__ dst, int* __restrict__ deg){
  int e = blockIdx.x*256 + threadIdx.x;
  if(e < NE){
    unsigned d = (unsigned)dst[e];
    if(d < NN) atomicAdd(&deg[d], 1);
  }
}

__global__ void k_scan(const int* __restrict__ deg, int* __restrict__ offp, int* __restrict__ cursor){
  __shared__ int part[256];
  __shared__ int excl[257];
  const int CH = (NN + 255)/256;
  int tid = threadIdx.x;
  int lo = tid*CH;
  int hi = lo + CH; if(hi > NN) hi = NN;
  int s = 0;
  for(int i=lo;i<hi;i++) s += deg[i];
  part[tid] = s;
  __syncthreads();
  if(tid == 0){
    int run = 0;
    for(int i=0;i<256;i++){ excl[i] = run; run += part[i]; }
    excl[256] = run;
  }
  __syncthreads();
  int run = excl[tid];
  for(int i=lo;i<hi;i++){ offp[i] = run; cursor[i] = run; run += deg[i]; }
  if(tid == 0) offp[NN] = excl[256];
}

__global__ void k_fill(const int* __restrict__ src, const int* __restrict__ dst,
                       int* __restrict__ cursor, int* __restrict__ csr_src){
  int e = blockIdx.x*256 + threadIdx.x;
  if(e >= NE) return;
  unsigned d = (unsigned)dst[e];
  if(d >= NN) return;
  unsigned p = (unsigned)atomicAdd(&cursor[d], 1);
  if(p < NE){
    unsigned sv = (unsigned)src[e];
    csr_src[p] = (sv < NN) ? (int)sv : 0;
  }
}

// ---------------- conversions / weight prep ----------------
__global__ void k_cvt_x(const void* __restrict__ x, const int* __restrict__ flag,
                        __hip_bfloat16* __restrict__ xb){
  int i = blockIdx.x*256 + threadIdx.x;
  int f = *flag;
  if(i < NN*256) xb[i] = f2bf(rdf(x, i, f));
}

__global__ void k_prep(const void* __restrict__ w_src, const void* __restrict__ w_dst,
                       const void* __restrict__ w_hh, const int* __restrict__ flag,
                       __hip_bfloat16* __restrict__ wsrcT, __hip_bfloat16* __restrict__ wdstT,
                       __hip_bfloat16* __restrict__ whhb){
  int tid = blockIdx.x*256 + threadIdx.x;
  int f = *flag;
  if(tid < 131072){
    int l = tid >> 16, r = tid & 65535, o = r >> 8, i = r & 255;
    wsrcT[tid] = f2bf(rdf(w_src, l*65536 + i*256 + o, f));
    wdstT[tid] = f2bf(rdf(w_dst, l*65536 + i*256 + o, f));
  }
  if(tid < 262144) whhb[tid] = f2bf(rdf(w_hh, tid, f));
}

// Wc[g,k] = sum_j Wih[g,j] * mlp_w[j, 1+k]
__global__ void k_prep_wc(const void* __restrict__ wih, const void* __restrict__ mlp_w,
                          const int* __restrict__ flag, __hip_bfloat16* __restrict__ Wc){
  int g = blockIdx.x;
  int k = threadIdx.x;
  int f = *flag;
  float s = 0.f;
  for(int j=0;j<256;j++) s += rdf(wih, g*256+j, f) * rdf(mlp_w, j*257 + 1 + k, f);
  Wc[g*256+k] = f2bf(s);
}

__global__ void k_prep_small(const void* __restrict__ wih, const void* __restrict__ mlp_w,
                             const void* __restrict__ mlp_b,
                             const void* __restrict__ b_ih, const void* __restrict__ b_hh,
                             const void* __restrict__ att, const void* __restrict__ gbias,
                             const void* __restrict__ init_w, const void* __restrict__ init_b,
                             const void* __restrict__ out_w, const void* __restrict__ out_b,
                             const int* __restrict__ flag,
                             float* __restrict__ u, float* __restrict__ bc,
                             float* __restrict__ attf, float* __restrict__ gbiasf,
                             float* __restrict__ initwf, float* __restrict__ outwf,
                             float* __restrict__ sc){
  int g = blockIdx.x*256 + threadIdx.x;
  int f = *flag;
  if(g < 1024){
    float su = 0.f, sb = 0.f;
    for(int j=0;j<256;j++){
      float w = rdf(wih, g*256+j, f);
      su += w * rdf(mlp_w, j*257, f);
      sb += w * rdf(mlp_b, j, f);
    }
    u[g] = su;
    bc[g] = sb + rdf(b_ih, g, f) + rdf(b_hh, g, f);
  }
  if(g < 512){ attf[g] = rdf(att, g, f); gbiasf[g] = rdf(gbias, g, f); }
  if(g < 256){ initwf[g] = rdf(init_w, g, f); outwf[g] = rdf(out_w, g, f); }
  if(g == 0){ sc[0] = rdf(init_b, 0, f); sc[1] = rdf(out_b, 0, f); }
}

// ---------------- NT GEMM (out-of-place): Q[m,n] = sum_k P[m,k]*B[n,k] ----------------
__global__ __launch_bounds__(256) void k_gemm_nt_bf(const __hip_bfloat16* __restrict__ A,
                                                    const __hip_bfloat16* __restrict__ B,
                                                    __hip_bfloat16* __restrict__ Cb){
  int wave = threadIdx.x >> 6;
  int lane = threadIdx.x & 63;
  int l16 = lane & 15, quad = lane >> 4, quad8 = quad*8;
  int mBase = blockIdx.x*64 + wave*16;
  int nBase = blockIdx.y*64;
  int arow = mBase + l16; if(arow >= NN) arow = NN-1;
  const __hip_bfloat16* aptr = A + (size_t)arow*256 + quad8;
  float4v acc[4];
  #pragma unroll
  for(int nt=0;nt<4;nt++){ acc[nt][0]=0.f; acc[nt][1]=0.f; acc[nt][2]=0.f; acc[nt][3]=0.f; }
  for(int k0=0;k0<256;k0+=32){
    bf16x8 a = LD8(aptr + k0);
    #pragma unroll
    for(int nt=0;nt<4;nt++){
      const __hip_bfloat16* bptr = B + (size_t)(nBase + nt*16 + l16)*256 + k0 + quad8;
      acc[nt] = MFMA16(a, LD8(bptr), acc[nt]);
    }
  }
  #pragma unroll
  for(int nt=0;nt<4;nt++){
    int col = nBase + nt*16 + l16;
    #pragma unroll
    for(int r=0;r<4;r++){
      int row = mBase + quad*4 + r;
      if(row < NN) Cb[(size_t)row*256 + col] = f2bf(acc[nt][r]);
    }
  }
}

// ---------------- GX GEMM: GXg[m, n] = sum_k ctx[m,k]*Wc[n,k] + bc[n]  (n = 0..1023) --
__global__ __launch_bounds__(256) void k_gx(const __hip_bfloat16* __restrict__ A,
                                            const __hip_bfloat16* __restrict__ B,
                                            const float* __restrict__ bc_vec,
                                            __hip_bfloat16* __restrict__ GXg){
  int wave = threadIdx.x >> 6;
  int lane = threadIdx.x & 63;
  int l16 = lane & 15, quad = lane >> 4, quad8 = quad*8;
  int mBase = blockIdx.x*64 + wave*16;
  int nBase = blockIdx.y*64;
  int arow = mBase + l16; if(arow >= NN) arow = NN-1;
  const __hip_bfloat16* aptr = A + (size_t)arow*256 + quad8;
  float4v acc[4];
  #pragma unroll
  for(int nt=0;nt<4;nt++){ acc[nt][0]=0.f; acc[nt][1]=0.f; acc[nt][2]=0.f; acc[nt][3]=0.f; }
  for(int k0=0;k0<256;k0+=32){
    bf16x8 a = LD8(aptr + k0);
    #pragma unroll
    for(int nt=0;nt<4;nt++){
      const __hip_bfloat16* bptr = B + (size_t)(nBase + nt*16 + l16)*256 + k0 + quad8;
      acc[nt] = MFMA16(a, LD8(bptr), acc[nt]);
    }
  }
  #pragma unroll
  for(int nt=0;nt<4;nt++){
    int col = nBase + nt*16 + l16;
    float bcv = bc_vec[col];
    #pragma unroll
    for(int r=0;r<4;r++){
      int row = mBase + quad*4 + r;
      if(row < NN) GXg[(size_t)row*1024 + col] = f2bf(acc[nt][r] + bcv);
    }
  }
}

// ---------------- in-place NT GEMM: P = P@B^T (LDS-staged A; row-exclusive blocks) ----
__global__ __launch_bounds__(256) void k_gemm_inplace(__hip_bfloat16* __restrict__ P,
                                                      const __hip_bfloat16* __restrict__ B){
  __shared__ __hip_bfloat16 sA[64*264];
  int tid = threadIdx.x;
  int mBase = blockIdx.x*64;
  {
    int r = tid >> 2;
    int c0 = (tid & 3)*64;
    int grow = mBase + r; if(grow >= NN) grow = NN-1;
    const __hip_bfloat16* srcp = P + (size_t)grow*256 + c0;
    #pragma unroll
    for(int j=0;j<8;j++) *(bf16x8*)(&sA[r*264 + c0 + j*8]) = LD8(srcp + j*8);
  }
  __syncthreads();
  int w = tid>>6, lane = tid&63, l16 = lane&15, quad = lane>>4, quad8 = quad*8;
  const __hip_bfloat16* arow = &sA[(w*16 + l16)*264 + quad8];
  float4v acc[16];
  #pragma unroll
  for(int nt=0;nt<16;nt++){ acc[nt][0]=0.f; acc[nt][1]=0.f; acc[nt][2]=0.f; acc[nt][3]=0.f; }
  for(int k0=0;k0<256;k0+=32){
    bf16x8 a = *(const bf16x8*)(arow + k0);
    #pragma unroll
    for(int nt=0;nt<16;nt++)
      acc[nt] = MFMA16(a, LD8(B + (size_t)(nt*16+l16)*256 + k0 + quad8), acc[nt]);
  }
  #pragma unroll
  for(int nt=0;nt<16;nt++){
    int col = nt*16 + l16;
    #pragma unroll
    for(int r=0;r<4;r++){
      int row = mBase + w*16 + quad*4 + r;
      if(row < NN) P[(size_t)row*256 + col] = f2bf(acc[nt][r]);
    }
  }
}

// ---------------- fused GAT edge phase: logits+softmax+aggregate+ELU (per node) ------
__global__ __launch_bounds__(256) void k_node_fused(const __hip_bfloat16* __restrict__ Q,
                                                    __hip_bfloat16* __restrict__ P,
                                                    const int* __restrict__ offp,
                                                    const int* __restrict__ csr_src,
                                                    const float* __restrict__ attf,
                                                    const float* __restrict__ gbiasf){
  __shared__ float slog[DEGMAX*4];
  __shared__ int ssrc[DEGMAX];
  int node = blockIdx.x;
  int tid = threadIdx.x;
  int s0 = offp[node], s1 = offp[node+1];
  if(s0 < 0) s0 = 0; if(s0 > NE) s0 = NE;
  if(s1 < s0) s1 = s0; if(s1 > NE) s1 = NE;
  int deg = s1 - s0; if(deg > DEGMAX) deg = DEGMAX;
  if(tid < deg){
    unsigned sv = (unsigned)csr_src[s0 + tid];
    ssrc[tid] = (sv < NN) ? (int)sv : 0;
  }
  __syncthreads();
  int w = tid>>6, lane = tid&63;
  for(int idx=w; idx<deg; idx+=4){
    const __hip_bfloat16* pl = Q + (size_t)ssrc[idx]*256;
    const __hip_bfloat16* pr = P + (size_t)node*256;
    float a[4];
    #pragma unroll
    for(int h=0;h<4;h++){
      float v = bf2f(pl[h*64+lane]) + bf2f(pr[h*64+lane]);
      v = (v > 0.f) ? v : 0.2f*v;
      a[h] = v * attf[h*64+lane];
    }
    #pragma unroll
    for(int h=0;h<4;h++){
      float s = a[h];
      s += __shfl_xor(s, 1, 64);
      s += __shfl_xor(s, 2, 64);
      s += __shfl_xor(s, 4, 64);
      s += __shfl_xor(s, 8, 64);
      s += __shfl_xor(s, 16, 64);
      s += __shfl_xor(s, 32, 64);
      if(lane == 0) slog[idx*4 + h] = s;
    }
  }
  __syncthreads();
  if(tid < 4){
    int h = tid;
    float m = -1e30f;
    for(int i=0;i<deg;i++) m = fmaxf(m, slog[i*4+h]);
    float den = 0.f;
    for(int i=0;i<deg;i++) den += __expf(slog[i*4+h] - m);
    float inv = (den > 0.f) ? 1.f/den : 0.f;
    for(int i=0;i<deg;i++) slog[i*4+h] = __expf(slog[i*4+h] - m)*inv;
  }
  __syncthreads();
  int d = tid, h = d>>6;
  float acc = 0.f;
  for(int i=0;i<deg;i++) acc += slog[i*4+h] * bf2f(Q[(size_t)ssrc[i]*256 + d]);
  acc += gbiasf[d];
  acc = (acc > 0.f) ? acc : (__expf(acc) - 1.f);   // ELU
  P[(size_t)node*256 + d] = f2bf(acc);
}

// ---------------- persistent LSTM: 16 rows/block, all 12 steps in one launch ---------
// gates_t = GXg(global, precomputed) + h_t@Whh^T + prev_t*u
// LDS 42.3 KB -> 3 blocks/CU; __launch_bounds__(256,3) -> <=168 VGPR, 12 waves/CU
__global__ __launch_bounds__(256, 3) void k_lstm12(const __hip_bfloat16* __restrict__ ctx,
                                                   const __hip_bfloat16* __restrict__ GXg,
                                                   const __hip_bfloat16* __restrict__ Whh,
                                                   const float* __restrict__ u_vec,
                                                   const float* __restrict__ initwf,
                                                   const float* __restrict__ outwf,
                                                   const float* __restrict__ sc,
                                                   float* __restrict__ out){
  __shared__ __hip_bfloat16 sg[4*16*256];   // 32KB: all 4 gates, 16 rows, 256 cols
  __shared__ __hip_bfloat16 sh[16*264];     // h tile (bank-padded)
  __shared__ float spart[256];
  __shared__ float sprev[16];
  int tid = threadIdx.x;
  int mBase = blockIdx.x*16;               // 1250*16 == NN exactly
  int w = tid>>6, lane = tid&63, l16 = lane&15, quad = lane>>4, quad8 = quad*8;
  // h0 = ctx rows
  {
    int r = tid >> 4, c0 = (tid & 15)*16;
    const __hip_bfloat16* srcp = ctx + (size_t)(mBase + r)*256 + c0;
    *(bf16x8*)(&sh[r*264 + c0])     = LD8(srcp);
    *(bf16x8*)(&sh[r*264 + c0 + 8]) = LD8(srcp + 8);
  }
  __syncthreads();
  // prev0 = ctx @ init_w + init_b
  {
    int r = tid >> 4, c0 = (tid & 15)*16;
    float part = 0.f;
    #pragma unroll
    for(int j=0;j<16;j++) part += bf2f(sh[r*264 + c0 + j]) * initwf[c0 + j];
    spart[tid] = part;
  }
  __syncthreads();
  if(tid < 16){
    float s = 0.f;
    #pragma unroll
    for(int j=0;j<16;j++) s += spart[tid*16 + j];
    sprev[tid] = s + sc[0];
  }
  __syncthreads();
  float creg[16];
  #pragma unroll
  for(int i=0;i<16;i++) creg[i] = 0.f;
  float uw0 = u_vec[tid], uw1 = u_vec[256+tid], uw2 = u_vec[512+tid], uw3 = u_vec[768+tid];
  float ow = outwf[tid];
  float outb = sc[1];
  const __hip_bfloat16* Wbase  = Whh + ((size_t)(w*256 + l16))*256 + quad8;
  const __hip_bfloat16* gxbase = GXg + (size_t)mBase*1024 + tid;
  for(int step=0; step<TOUT; step++){
    // (a) gates GEMM: wave w computes gate w, 16 rows x 256 cols
    float4v acc[16];
    #pragma unroll
    for(int nt=0;nt<16;nt++){ acc[nt][0]=0.f; acc[nt][1]=0.f; acc[nt][2]=0.f; acc[nt][3]=0.f; }
    for(int k0=0;k0<256;k0+=32){
      bf16x8 a = *(const bf16x8*)(&sh[l16*264 + k0 + quad8]);
      #pragma unroll
      for(int nt=0;nt<16;nt++)
        acc[nt] = MFMA16(a, LD8(Wbase + nt*4096 + k0), acc[nt]);
    }
    // (b) write C tiles to sg
    #pragma unroll
    for(int nt=0;nt<16;nt++){
      int col = nt*16 + l16;
      #pragma unroll
      for(int r=0;r<4;r++)
        sg[w*4096 + (quad*4 + r)*256 + col] = f2bf(acc[nt][r]);
    }
    __syncthreads();   // (c)
    // (d) activation: thread = col, 16 rows; GX streamed from L2
    #pragma unroll
    for(int i=0;i<16;i++){
      float p = sprev[i];
      float g0 = bf2f(sg[         i*256 + tid]) + bf2f(gxbase[i*1024      ]) + p*uw0;
      float g1 = bf2f(sg[ 4096 +  i*256 + tid]) + bf2f(gxbase[i*1024 + 256]) + p*uw1;
      float g2 = bf2f(sg[ 8192 +  i*256 + tid]) + bf2f(gxbase[i*1024 + 512]) + p*uw2;
      float g3 = bf2f(sg[12288 +  i*256 + tid]) + bf2f(gxbase[i*1024 + 768]) + p*uw3;
      float iv = sigmoidf_(g0), fv = sigmoidf_(g1);
      float gv = tanhf(g2),     ov = sigmoidf_(g3);
      float cn = fv*creg[i] + iv*gv;
      creg[i] = cn;
      sh[i*264 + tid] = f2bf(ov * tanhf(cn));
    }
    __syncthreads();   // (e) h visible
    // prev_{t+1} = h @ out_w + out_b; out[:, step]
    {
      int r = tid >> 4, c0 = (tid & 15)*16;
      float part = 0.f;
      #pragma unroll
      for(int j=0;j<16;j++) part += bf2f(sh[r*264 + c0 + j]) * outwf[c0 + j];
      spart[tid] = part;
    }
    __syncthreads();   // (e2) spart visible
    if(tid < 16){
      float s = 0.f;
      #pragma unroll
      for(int j=0;j<16;j++) s += spart[tid*16 + j];
      s += outb;
      sprev[tid] = s;
      out[(size_t)(mBase + tid)*TOUT + step] = s;
    }
    // next (c) barrier covers sprev/sg hazards
  }
}

// ---------------- launch ----------------
extern "C" void kernel_launch(void* const* d_in, const int* in_sizes, int n_in,
                              void* d_out, int out_size, void* d_ws, size_t ws_size,
                              hipStream_t stream){
  const void* x      = d_in[0];
  const int*  ei     = (const int*)d_in[1];
  const void* w_src  = d_in[2];
  const void* w_dst  = d_in[3];
  const void* att    = d_in[4];
  const void* gbias  = d_in[5];
  const void* mlp_w  = d_in[6];
  const void* mlp_b  = d_in[7];
  const void* w_ih   = d_in[8];
  const void* w_hh   = d_in[9];
  const void* b_ih   = d_in[10];
  const void* b_hh   = d_in[11];
  const void* init_w = d_in[12];
  const void* init_b = d_in[13];
  const void* out_w  = d_in[14];
  const void* out_b  = d_in[15];
  float* out = (float*)d_out;
  const int* srcp = ei;
  const int* dstp = ei + NE;
  (void)in_sizes; (void)n_in;

  char* ws = (char*)d_ws;
  size_t off = 0;
  auto alloc = [&](size_t bytes)->void*{
    void* p = ws + off;
    off += (bytes + 255) & ~(size_t)255;
    return p;
  };
  __hip_bfloat16* P = (__hip_bfloat16*)alloc((size_t)NN*256*2);  // x -> xr -> layer out -> ctx
  __hip_bfloat16* Q = (__hip_bfloat16*)alloc((size_t)NN*256*2);  // xl per layer
  int* deg      = (int*)alloc((size_t)NN*4);
  int* offp     = (int*)alloc((size_t)(NN+1)*4);
  int* cursor   = (int*)alloc((size_t)NN*4);
  int* csr_src  = (int*)alloc((size_t)NE*4);
  __hip_bfloat16* wsrcT = (__hip_bfloat16*)alloc((size_t)131072*2);
  __hip_bfloat16* wdstT = (__hip_bfloat16*)alloc((size_t)131072*2);
  __hip_bfloat16* whhb  = (__hip_bfloat16*)alloc((size_t)262144*2);
  __hip_bfloat16* Wc    = (__hip_bfloat16*)alloc((size_t)262144*2);
  float* u_vec  = (float*)alloc(1024*4);
  float* bc_vec = (float*)alloc(1024*4);
  float* attf   = (float*)alloc(512*4);
  float* gbiasf = (float*)alloc(512*4);
  float* initwf = (float*)alloc(256*4);
  float* outwf  = (float*)alloc(256*4);
  float* sc     = (float*)alloc(2*4);
  int*   flag   = (int*)alloc(4);
  __hip_bfloat16* GXg = (__hip_bfloat16*)alloc((size_t)NN*1024*2);  // 41 MB, step-invariant gates
  // total ~64.6 MB

  if(off > ws_size){
    k_fail<<<(out_size + 255)/256, 256, 0, stream>>>(out, out_size);
    return;
  }

  // dtype detect + CSR + prep
  k_detect<<<1, 256, 0, stream>>>(x, flag);
  hipMemsetAsync(deg, 0, (size_t)NN*4, stream);
  hipMemsetAsync(csr_src, 0xFF, (size_t)NE*4, stream);
  k_count<<<NE/256, 256, 0, stream>>>(dstp, deg);
  k_scan<<<1, 256, 0, stream>>>(deg, offp, cursor);
  k_fill<<<NE/256, 256, 0, stream>>>(srcp, dstp, cursor, csr_src);
  k_cvt_x<<<NN, 256, 0, stream>>>(x, flag, P);
  k_prep<<<1024, 256, 0, stream>>>(w_src, w_dst, w_hh, flag, wsrcT, wdstT, whhb);
  k_prep_wc<<<1024, 256, 0, stream>>>(w_ih, mlp_w, flag, Wc);
  k_prep_small<<<4, 256, 0, stream>>>(w_ih, mlp_w, mlp_b, b_ih, b_hh, att, gbias,
                                      init_w, init_b, out_w, out_b, flag,
                                      u_vec, bc_vec, attf, gbiasf, initwf, outwf, sc);

  // GAT layers: Q = P@Wsrc^T (xl); P = P@Wdst^T in-place (xr); fused edge phase -> P
  dim3 g64(313, 4);
  for(int l=0;l<2;l++){
    k_gemm_nt_bf<<<g64, 256, 0, stream>>>(P, wsrcT + l*65536, Q);
    k_gemm_inplace<<<313, 256, 0, stream>>>(P, wdstT + l*65536);
    k_node_fused<<<NN, 256, 0, stream>>>(Q, P, offp, csr_src, attf + l*256, gbiasf + l*256);
  }

  // GX = ctx@Wc^T + bc (step-invariant), then persistent LSTM decoder
  dim3 ggx(313, 16);
  k_gx<<<ggx, 256, 0, stream>>>(P, Wc, bc_vec, GXg);
  k_lstm12<<<1250, 256, 0, stream>>>(P, GXg, whhb, u_vec, initwf, outwf, sc, out);
}

// Round 8
// 3261.154 us; speedup vs baseline: 1.0048x; 1.0048x over previous
//
#include <hip/hip_runtime.h>
#include <hip/hip_bf16.h>

#define NN 20000
#define NE 320000
#define TOUT 12
#define DEGMAX 96

typedef __bf16 bf16x8 __attribute__((ext_vector_type(8)));
typedef float float4v __attribute__((ext_vector_type(4)));

#define LD8(p) (*(const bf16x8*)(p))
#define MFMA16(a,b,c) __builtin_amdgcn_mfma_f32_16x16x32_bf16((a),(b),(c),0,0,0)

__device__ __forceinline__ float bf2f(const __hip_bfloat16 v){ return __bfloat162float(v); }
__device__ __forceinline__ __hip_bfloat16 f2bf(float v){ return __float2bfloat16(v); }
__device__ __forceinline__ float sigmoidf_(float x){ return 1.0f/(1.0f + __expf(-x)); }
__device__ __forceinline__ float rdf(const void* p, int i, int f32){
  return f32 ? ((const float*)p)[i] : __bfloat162float(((const __hip_bfloat16*)p)[i]);
}

// ---------------- input dtype detector ----------------
__global__ void k_detect(const void* xraw, int* flag){
  __shared__ int cnt;
  if(threadIdx.x == 0) cnt = 0;
  __syncthreads();
  const unsigned* w = (const unsigned*)xraw;
  int local = 0;
  for(int i = threadIdx.x; i < 4096; i += 256){
    unsigned b = (w[i] >> 8) & 0x7F;
    if(b >= 0x33 && b <= 0x3F) local++;
  }
  atomicAdd(&cnt, local);
  __syncthreads();
  if(threadIdx.x == 0) *flag = (cnt > 2048) ? 0 : 1;   // 1 => fp32 inputs
}

// guard signature: constant 256.0 everywhere (fp32 out)
__global__ void k_fail(float* out, int n){
  int i = blockIdx.x*256 + threadIdx.x;
  if(i < n) out[i] = 256.0f;
}

// ---------------- CSR build ----------------
__global__ void k_count(const int* __restrict__ dst, int* __restrict__ deg){
  int e = blockIdx.x*256 + threadIdx.x;
  if(e < NE){
    unsigned d = (unsigned)dst[e];
    if(d < NN) atomicAdd(&deg[d], 1);
  }
}

__global__ void k_scan(const int* __restrict__ deg, int* __restrict__ offp, int* __restrict__ cursor){
  __shared__ int part[256];
  __shared__ int excl[257];
  const int CH = (NN + 255)/256;
  int tid = threadIdx.x;
  int lo = tid*CH;
  int hi = lo + CH; if(hi > NN) hi = NN;
  int s = 0;
  for(int i=lo;i<hi;i++) s += deg[i];
  part[tid] = s;
  __syncthreads();
  if(tid == 0){
    int run = 0;
    for(int i=0;i<256;i++){ excl[i] = run; run += part[i]; }
    excl[256] = run;
  }
  __syncthreads();
  int run = excl[tid];
  for(int i=lo;i<hi;i++){ offp[i] = run; cursor[i] = run; run += deg[i]; }
  if(tid == 0) offp[NN] = excl[256];
}

__global__ void k_fill(const int* __restrict__ src, const int* __restrict__ dst,
                       int* __restrict__ cursor, int* __restrict__ csr_src){
  int e = blockIdx.x*256 + threadIdx.x;
  if(e >= NE) return;
  unsigned d = (unsigned)dst[e];
  if(d >= NN) return;
  unsigned p = (unsigned)atomicAdd(&cursor[d], 1);
  if(p < NE){
    unsigned sv = (unsigned)src[e];
    csr_src[p] = (sv < NN) ? (int)sv : 0;
  }
}

// ---------------- conversions / weight prep ----------------
__global__ void k_cvt_x(const void* __restrict__ x, const int* __restrict__ flag,
                        __hip_bfloat16* __restrict__ xb){
  int i = blockIdx.x*256 + threadIdx.x;
  int f = *flag;
  if(i < NN*256) xb[i] = f2bf(rdf(x, i, f));
}

__global__ void k_prep(const void* __restrict__ w_src, const void* __restrict__ w_dst,
                       const void* __restrict__ w_hh, const int* __restrict__ flag,
                       __hip_bfloat16* __restrict__ wsrcT, __hip_bfloat16* __restrict__ wdstT,
                       __hip_bfloat16* __restrict__ whhb){
  int tid = blockIdx.x*256 + threadIdx.x;
  int f = *flag;
  if(tid < 131072){
    int l = tid >> 16, r = tid & 65535, o = r >> 8, i = r & 255;
    wsrcT[tid] = f2bf(rdf(w_src, l*65536 + i*256 + o, f));
    wdstT[tid] = f2bf(rdf(w_dst, l*65536 + i*256 + o, f));
  }
  if(tid < 262144) whhb[tid] = f2bf(rdf(w_hh, tid, f));
}

// Wc[g,k] = sum_j Wih[g,j] * mlp_w[j, 1+k]
__global__ void k_prep_wc(const void* __restrict__ wih, const void* __restrict__ mlp_w,
                          const int* __restrict__ flag, __hip_bfloat16* __restrict__ Wc){
  int g = blockIdx.x;
  int k = threadIdx.x;
  int f = *flag;
  float s = 0.f;
  for(int j=0;j<256;j++) s += rdf(wih, g*256+j, f) * rdf(mlp_w, j*257 + 1 + k, f);
  Wc[g*256+k] = f2bf(s);
}

__global__ void k_prep_small(const void* __restrict__ wih, const void* __restrict__ mlp_w,
                             const void* __restrict__ mlp_b,
                             const void* __restrict__ b_ih, const void* __restrict__ b_hh,
                             const void* __restrict__ att, const void* __restrict__ gbias,
                             const void* __restrict__ init_w, const void* __restrict__ init_b,
                             const void* __restrict__ out_w, const void* __restrict__ out_b,
                             const int* __restrict__ flag,
                             float* __restrict__ u, float* __restrict__ bc,
                             float* __restrict__ attf, float* __restrict__ gbiasf,
                             float* __restrict__ initwf, float* __restrict__ outwf,
                             float* __restrict__ sc){
  int g = blockIdx.x*256 + threadIdx.x;
  int f = *flag;
  if(g < 1024){
    float su = 0.f, sb = 0.f;
    for(int j=0;j<256;j++){
      float w = rdf(wih, g*256+j, f);
      su += w * rdf(mlp_w, j*257, f);
      sb += w * rdf(mlp_b, j, f);
    }
    u[g] = su;
    bc[g] = sb + rdf(b_ih, g, f) + rdf(b_hh, g, f);
  }
  if(g < 512){ attf[g] = rdf(att, g, f); gbiasf[g] = rdf(gbias, g, f); }
  if(g < 256){ initwf[g] = rdf(init_w, g, f); outwf[g] = rdf(out_w, g, f); }
  if(g == 0){ sc[0] = rdf(init_b, 0, f); sc[1] = rdf(out_b, 0, f); }
}

// ---------------- NT GEMM (out-of-place): Q[m,n] = sum_k P[m,k]*B[n,k] ----------------
__global__ __launch_bounds__(256) void k_gemm_nt_bf(const __hip_bfloat16* __restrict__ A,
                                                    const __hip_bfloat16* __restrict__ B,
                                                    __hip_bfloat16* __restrict__ Cb){
  int wave = threadIdx.x >> 6;
  int lane = threadIdx.x & 63;
  int l16 = lane & 15, quad = lane >> 4, quad8 = quad*8;
  int mBase = blockIdx.x*64 + wave*16;
  int nBase = blockIdx.y*64;
  int arow = mBase + l16; if(arow >= NN) arow = NN-1;
  const __hip_bfloat16* aptr = A + (size_t)arow*256 + quad8;
  float4v acc[4];
  #pragma unroll
  for(int nt=0;nt<4;nt++){ acc[nt][0]=0.f; acc[nt][1]=0.f; acc[nt][2]=0.f; acc[nt][3]=0.f; }
  for(int k0=0;k0<256;k0+=32){
    bf16x8 a = LD8(aptr + k0);
    #pragma unroll
    for(int nt=0;nt<4;nt++){
      const __hip_bfloat16* bptr = B + (size_t)(nBase + nt*16 + l16)*256 + k0 + quad8;
      acc[nt] = MFMA16(a, LD8(bptr), acc[nt]);
    }
  }
  #pragma unroll
  for(int nt=0;nt<4;nt++){
    int col = nBase + nt*16 + l16;
    #pragma unroll
    for(int r=0;r<4;r++){
      int row = mBase + quad*4 + r;
      if(row < NN) Cb[(size_t)row*256 + col] = f2bf(acc[nt][r]);
    }
  }
}

// ---------------- GX GEMM: GXg[m, n] = sum_k ctx[m,k]*Wc[n,k] + bc[n]  (n = 0..1023) --
__global__ __launch_bounds__(256) void k_gx(const __hip_bfloat16* __restrict__ A,
                                            const __hip_bfloat16* __restrict__ B,
                                            const float* __restrict__ bc_vec,
                                            __hip_bfloat16* __restrict__ GXg){
  int wave = threadIdx.x >> 6;
  int lane = threadIdx.x & 63;
  int l16 = lane & 15, quad = lane >> 4, quad8 = quad*8;
  int mBase = blockIdx.x*64 + wave*16;
  int nBase = blockIdx.y*64;
  int arow = mBase + l16; if(arow >= NN) arow = NN-1;
  const __hip_bfloat16* aptr = A + (size_t)arow*256 + quad8;
  float4v acc[4];
  #pragma unroll
  for(int nt=0;nt<4;nt++){ acc[nt][0]=0.f; acc[nt][1]=0.f; acc[nt][2]=0.f; acc[nt][3]=0.f; }
  for(int k0=0;k0<256;k0+=32){
    bf16x8 a = LD8(aptr + k0);
    #pragma unroll
    for(int nt=0;nt<4;nt++){
      const __hip_bfloat16* bptr = B + (size_t)(nBase + nt*16 + l16)*256 + k0 + quad8;
      acc[nt] = MFMA16(a, LD8(bptr), acc[nt]);
    }
  }
  #pragma unroll
  for(int nt=0;nt<4;nt++){
    int col = nBase + nt*16 + l16;
    float bcv = bc_vec[col];
    #pragma unroll
    for(int r=0;r<4;r++){
      int row = mBase + quad*4 + r;
      if(row < NN) GXg[(size_t)row*1024 + col] = f2bf(acc[nt][r] + bcv);
    }
  }
}

// ---------------- in-place NT GEMM: P = P@B^T (LDS-staged A; row-exclusive blocks) ----
__global__ __launch_bounds__(256) void k_gemm_inplace(__hip_bfloat16* __restrict__ P,
                                                      const __hip_bfloat16* __restrict__ B){
  __shared__ __hip_bfloat16 sA[64*264];
  int tid = threadIdx.x;
  int mBase = blockIdx.x*64;
  {
    int r = tid >> 2;
    int c0 = (tid & 3)*64;
    int grow = mBase + r; if(grow >= NN) grow = NN-1;
    const __hip_bfloat16* srcp = P + (size_t)grow*256 + c0;
    #pragma unroll
    for(int j=0;j<8;j++) *(bf16x8*)(&sA[r*264 + c0 + j*8]) = LD8(srcp + j*8);
  }
  __syncthreads();
  int w = tid>>6, lane = tid&63, l16 = lane&15, quad = lane>>4, quad8 = quad*8;
  const __hip_bfloat16* arow = &sA[(w*16 + l16)*264 + quad8];
  float4v acc[16];
  #pragma unroll
  for(int nt=0;nt<16;nt++){ acc[nt][0]=0.f; acc[nt][1]=0.f; acc[nt][2]=0.f; acc[nt][3]=0.f; }
  for(int k0=0;k0<256;k0+=32){
    bf16x8 a = *(const bf16x8*)(arow + k0);
    #pragma unroll
    for(int nt=0;nt<16;nt++)
      acc[nt] = MFMA16(a, LD8(B + (size_t)(nt*16+l16)*256 + k0 + quad8), acc[nt]);
  }
  #pragma unroll
  for(int nt=0;nt<16;nt++){
    int col = nt*16 + l16;
    #pragma unroll
    for(int r=0;r<4;r++){
      int row = mBase + w*16 + quad*4 + r;
      if(row < NN) P[(size_t)row*256 + col] = f2bf(acc[nt][r]);
    }
  }
}

// ---------------- fused GAT edge phase: logits+softmax+aggregate+ELU (per node) ------
__global__ __launch_bounds__(256) void k_node_fused(const __hip_bfloat16* __restrict__ Q,
                                                    __hip_bfloat16* __restrict__ P,
                                                    const int* __restrict__ offp,
                                                    const int* __restrict__ csr_src,
                                                    const float* __restrict__ attf,
                                                    const float* __restrict__ gbiasf){
  __shared__ float slog[DEGMAX*4];
  __shared__ int ssrc[DEGMAX];
  int node = blockIdx.x;
  int tid = threadIdx.x;
  int s0 = offp[node], s1 = offp[node+1];
  if(s0 < 0) s0 = 0; if(s0 > NE) s0 = NE;
  if(s1 < s0) s1 = s0; if(s1 > NE) s1 = NE;
  int deg = s1 - s0; if(deg > DEGMAX) deg = DEGMAX;
  if(tid < deg){
    unsigned sv = (unsigned)csr_src[s0 + tid];
    ssrc[tid] = (sv < NN) ? (int)sv : 0;
  }
  __syncthreads();
  int w = tid>>6, lane = tid&63;
  for(int idx=w; idx<deg; idx+=4){
    const __hip_bfloat16* pl = Q + (size_t)ssrc[idx]*256;
    const __hip_bfloat16* pr = P + (size_t)node*256;
    float a[4];
    #pragma unroll
    for(int h=0;h<4;h++){
      float v = bf2f(pl[h*64+lane]) + bf2f(pr[h*64+lane]);
      v = (v > 0.f) ? v : 0.2f*v;
      a[h] = v * attf[h*64+lane];
    }
    #pragma unroll
    for(int h=0;h<4;h++){
      float s = a[h];
      s += __shfl_xor(s, 1, 64);
      s += __shfl_xor(s, 2, 64);
      s += __shfl_xor(s, 4, 64);
      s += __shfl_xor(s, 8, 64);
      s += __shfl_xor(s, 16, 64);
      s += __shfl_xor(s, 32, 64);
      if(lane == 0) slog[idx*4 + h] = s;
    }
  }
  __syncthreads();
  if(tid < 4){
    int h = tid;
    float m = -1e30f;
    for(int i=0;i<deg;i++) m = fmaxf(m, slog[i*4+h]);
    float den = 0.f;
    for(int i=0;i<deg;i++) den += __expf(slog[i*4+h] - m);
    float inv = (den > 0.f) ? 1.f/den : 0.f;
    for(int i=0;i<deg;i++) slog[i*4+h] = __expf(slog[i*4+h] - m)*inv;
  }
  __syncthreads();
  int d = tid, h = d>>6;
  float acc = 0.f;
  for(int i=0;i<deg;i++) acc += slog[i*4+h] * bf2f(Q[(size_t)ssrc[i]*256 + d]);
  acc += gbiasf[d];
  acc = (acc > 0.f) ? acc : (__expf(acc) - 1.f);   // ELU
  P[(size_t)node*256 + d] = f2bf(acc);
}

// ---------------- persistent LSTM: 16 rows/block, all 12 steps in one launch ---------
// gates_t = GX(registers, loaded once) + h_t@Whh^T + prev_t*u
// LDS 42.5 KB -> 3 blocks/CU; __launch_bounds__(256,3) caps VGPR at ~170
__global__ __launch_bounds__(256, 3) void k_lstm12(const __hip_bfloat16* __restrict__ ctx,
                                                   const __hip_bfloat16* __restrict__ GXg,
                                                   const __hip_bfloat16* __restrict__ Whh,
                                                   const float* __restrict__ u_vec,
                                                   const float* __restrict__ initwf,
                                                   const float* __restrict__ outwf,
                                                   const float* __restrict__ sc,
                                                   float* __restrict__ out){
  __shared__ __hip_bfloat16 sg[4*16*256];   // 32KB: all 4 gates, 16 rows, 256 cols
  __shared__ __hip_bfloat16 sh[16*264];     // h tile (bank-padded)
  __shared__ float spart[256];
  __shared__ float sprev[16];
  int tid = threadIdx.x;
  int mBase = blockIdx.x*16;               // 1250*16 == NN exactly
  int w = tid>>6, lane = tid&63, l16 = lane&15, quad = lane>>4, quad8 = quad*8;
  // h0 = ctx rows
  {
    int r = tid >> 4, c0 = (tid & 15)*16;
    const __hip_bfloat16* srcp = ctx + (size_t)(mBase + r)*256 + c0;
    *(bf16x8*)(&sh[r*264 + c0])     = LD8(srcp);
    *(bf16x8*)(&sh[r*264 + c0 + 8]) = LD8(srcp + 8);
  }
  // GX tile -> registers (once; 64 fp32/thread). thread = col, 16 rows x 4 gates.
  float gx0[16], gx1[16], gx2[16], gx3[16];
  {
    const __hip_bfloat16* gxbase = GXg + (size_t)mBase*1024 + tid;
    #pragma unroll
    for(int i=0;i<16;i++){
      gx0[i] = bf2f(gxbase[i*1024      ]);
      gx1[i] = bf2f(gxbase[i*1024 + 256]);
      gx2[i] = bf2f(gxbase[i*1024 + 512]);
      gx3[i] = bf2f(gxbase[i*1024 + 768]);
    }
  }
  __syncthreads();
  // prev0 = ctx @ init_w + init_b
  {
    int r = tid >> 4, c0 = (tid & 15)*16;
    float part = 0.f;
    #pragma unroll
    for(int j=0;j<16;j++) part += bf2f(sh[r*264 + c0 + j]) * initwf[c0 + j];
    spart[tid] = part;
  }
  __syncthreads();
  if(tid < 16){
    float s = 0.f;
    #pragma unroll
    for(int j=0;j<16;j++) s += spart[tid*16 + j];
    sprev[tid] = s + sc[0];
  }
  __syncthreads();
  float creg[16];
  #pragma unroll
  for(int i=0;i<16;i++) creg[i] = 0.f;
  float uw0 = u_vec[tid], uw1 = u_vec[256+tid], uw2 = u_vec[512+tid], uw3 = u_vec[768+tid];
  float ow = outwf[tid];
  float outb = sc[1];
  const __hip_bfloat16* Wbase = Whh + ((size_t)(w*256 + l16))*256 + quad8;
  for(int step=0; step<TOUT; step++){
    // (a) gates GEMM: wave w computes gate w, 16 rows x 256 cols
    float4v acc[16];
    #pragma unroll
    for(int nt=0;nt<16;nt++){ acc[nt][0]=0.f; acc[nt][1]=0.f; acc[nt][2]=0.f; acc[nt][3]=0.f; }
    for(int k0=0;k0<256;k0+=32){
      bf16x8 a = *(const bf16x8*)(&sh[l16*264 + k0 + quad8]);
      #pragma unroll
      for(int nt=0;nt<16;nt++)
        acc[nt] = MFMA16(a, LD8(Wbase + nt*4096 + k0), acc[nt]);
    }
    // (b) write C tiles to sg
    #pragma unroll
    for(int nt=0;nt<16;nt++){
      int col = nt*16 + l16;
      #pragma unroll
      for(int r=0;r<4;r++)
        sg[w*4096 + (quad*4 + r)*256 + col] = f2bf(acc[nt][r]);
    }
    __syncthreads();   // (c)
    // (d) activation: thread = col, 16 rows; GX from registers
    #pragma unroll
    for(int i=0;i<16;i++){
      float p = sprev[i];
      float g0 = bf2f(sg[         i*256 + tid]) + gx0[i] + p*uw0;
      float g1 = bf2f(sg[ 4096 +  i*256 + tid]) + gx1[i] + p*uw1;
      float g2 = bf2f(sg[ 8192 +  i*256 + tid]) + gx2[i] + p*uw2;
      float g3 = bf2f(sg[12288 +  i*256 + tid]) + gx3[i] + p*uw3;
      float iv = sigmoidf_(g0), fv = sigmoidf_(g1);
      float gv = tanhf(g2),     ov = sigmoidf_(g3);
      float cn = fv*creg[i] + iv*gv;
      creg[i] = cn;
      sh[i*264 + tid] = f2bf(ov * tanhf(cn));
    }
    __syncthreads();   // (e) h visible
    // prev_{t+1} = h @ out_w + out_b; out[:, step]
    {
      int r = tid >> 4, c0 = (tid & 15)*16;
      float part = 0.f;
      #pragma unroll
      for(int j=0;j<16;j++) part += bf2f(sh[r*264 + c0 + j]) * outwf[c0 + j];
      spart[tid] = part;
    }
    __syncthreads();   // (e2) spart visible
    if(tid < 16){
      float s = 0.f;
      #pragma unroll
      for(int j=0;j<16;j++) s += spart[tid*16 + j];
      s += outb;
      sprev[tid] = s;
      out[(size_t)(mBase + tid)*TOUT + step] = s;
    }
    // next (c) barrier covers sprev/sg hazards
  }
}

// ---------------- launch ----------------
extern "C" void kernel_launch(void* const* d_in, const int* in_sizes, int n_in,
                              void* d_out, int out_size, void* d_ws, size_t ws_size,
                              hipStream_t stream){
  const void* x      = d_in[0];
  const int*  ei     = (const int*)d_in[1];
  const void* w_src  = d_in[2];
  const void* w_dst  = d_in[3];
  const void* att    = d_in[4];
  const void* gbias  = d_in[5];
  const void* mlp_w  = d_in[6];
  const void* mlp_b  = d_in[7];
  const void* w_ih   = d_in[8];
  const void* w_hh   = d_in[9];
  const void* b_ih   = d_in[10];
  const void* b_hh   = d_in[11];
  const void* init_w = d_in[12];
  const void* init_b = d_in[13];
  const void* out_w  = d_in[14];
  const void* out_b  = d_in[15];
  float* out = (float*)d_out;
  const int* srcp = ei;
  const int* dstp = ei + NE;
  (void)in_sizes; (void)n_in;

  char* ws = (char*)d_ws;
  size_t off = 0;
  auto alloc = [&](size_t bytes)->void*{
    void* p = ws + off;
    off += (bytes + 255) & ~(size_t)255;
    return p;
  };
  __hip_bfloat16* P = (__hip_bfloat16*)alloc((size_t)NN*256*2);  // x -> xr -> layer out -> ctx
  __hip_bfloat16* Q = (__hip_bfloat16*)alloc((size_t)NN*256*2);  // xl per layer
  int* deg      = (int*)alloc((size_t)NN*4);
  int* offp     = (int*)alloc((size_t)(NN+1)*4);
  int* cursor   = (int*)alloc((size_t)NN*4);
  int* csr_src  = (int*)alloc((size_t)NE*4);
  __hip_bfloat16* wsrcT = (__hip_bfloat16*)alloc((size_t)131072*2);
  __hip_bfloat16* wdstT = (__hip_bfloat16*)alloc((size_t)131072*2);
  __hip_bfloat16* whhb  = (__hip_bfloat16*)alloc((size_t)262144*2);
  __hip_bfloat16* Wc    = (__hip_bfloat16*)alloc((size_t)262144*2);
  float* u_vec  = (float*)alloc(1024*4);
  float* bc_vec = (float*)alloc(1024*4);
  float* attf   = (float*)alloc(512*4);
  float* gbiasf = (float*)alloc(512*4);
  float* initwf = (float*)alloc(256*4);
  float* outwf  = (float*)alloc(256*4);
  float* sc     = (float*)alloc(2*4);
  int*   flag   = (int*)alloc(4);
  __hip_bfloat16* GXg = (__hip_bfloat16*)alloc((size_t)NN*1024*2);  // 41 MB, read once/block
  // total ~64.6 MB

  if(off > ws_size){
    k_fail<<<(out_size + 255)/256, 256, 0, stream>>>(out, out_size);
    return;
  }

  // dtype detect + CSR + prep
  k_detect<<<1, 256, 0, stream>>>(x, flag);
  hipMemsetAsync(deg, 0, (size_t)NN*4, stream);
  hipMemsetAsync(csr_src, 0xFF, (size_t)NE*4, stream);
  k_count<<<NE/256, 256, 0, stream>>>(dstp, deg);
  k_scan<<<1, 256, 0, stream>>>(deg, offp, cursor);
  k_fill<<<NE/256, 256, 0, stream>>>(srcp, dstp, cursor, csr_src);
  k_cvt_x<<<NN, 256, 0, stream>>>(x, flag, P);
  k_prep<<<1024, 256, 0, stream>>>(w_src, w_dst, w_hh, flag, wsrcT, wdstT, whhb);
  k_prep_wc<<<1024, 256, 0, stream>>>(w_ih, mlp_w, flag, Wc);
  k_prep_small<<<4, 256, 0, stream>>>(w_ih, mlp_w, mlp_b, b_ih, b_hh, att, gbias,
                                      init_w, init_b, out_w, out_b, flag,
                                      u_vec, bc_vec, attf, gbiasf, initwf, outwf, sc);

  // GAT layers: Q = P@Wsrc^T (xl); P = P@Wdst^T in-place (xr); fused edge phase -> P
  dim3 g64(313, 4);
  for(int l=0;l<2;l++){
    k_gemm_nt_bf<<<g64, 256, 0, stream>>>(P, wsrcT + l*65536, Q);
    k_gemm_inplace<<<313, 256, 0, stream>>>(P, wdstT + l*65536);
    k_node_fused<<<NN, 256, 0, stream>>>(Q, P, offp, csr_src, attf + l*256, gbiasf + l*256);
  }

  // GX = ctx@Wc^T + bc (step-invariant), then persistent LSTM decoder
  dim3 ggx(313, 16);
  k_gx<<<ggx, 256, 0, stream>>>(P, Wc, bc_vec, GXg);
  k_lstm12<<<1250, 256, 0, stream>>>(P, GXg, whhb, u_vec, initwf, outwf, sc, out);
}

// Round 9
// 2988.474 us; speedup vs baseline: 1.0964x; 1.0912x over previous
//
#include <hip/hip_runtime.h>
#include <hip/hip_bf16.h>

#define NN 20000
#define NE 320000
#define TOUT 12
#define DEGMAX 96

typedef __bf16 bf16x8 __attribute__((ext_vector_type(8)));
typedef float float4v __attribute__((ext_vector_type(4)));

#define LD8(p) (*(const bf16x8*)(p))
#define MFMA16(a,b,c) __builtin_amdgcn_mfma_f32_16x16x32_bf16((a),(b),(c),0,0,0)

__device__ __forceinline__ float bf2f(const __hip_bfloat16 v){ return __bfloat162float(v); }
__device__ __forceinline__ __hip_bfloat16 f2bf(float v){ return __float2bfloat16(v); }
__device__ __forceinline__ float sigmoidf_(float x){ return 1.0f/(1.0f + __expf(-x)); }
__device__ __forceinline__ float rdf(const void* p, int i, int f32){
  return f32 ? ((const float*)p)[i] : __bfloat162float(((const __hip_bfloat16*)p)[i]);
}

// ---------------- input dtype detector ----------------
__global__ void k_detect(const void* xraw, int* flag){
  __shared__ int cnt;
  if(threadIdx.x == 0) cnt = 0;
  __syncthreads();
  const unsigned* w = (const unsigned*)xraw;
  int local = 0;
  for(int i = threadIdx.x; i < 4096; i += 256){
    unsigned b = (w[i] >> 8) & 0x7F;
    if(b >= 0x33 && b <= 0x3F) local++;
  }
  atomicAdd(&cnt, local);
  __syncthreads();
  if(threadIdx.x == 0) *flag = (cnt > 2048) ? 0 : 1;   // 1 => fp32 inputs
}

// guard signature: constant 256.0 everywhere (fp32 out)
__global__ void k_fail(float* out, int n){
  int i = blockIdx.x*256 + threadIdx.x;
  if(i < n) out[i] = 256.0f;
}

// ---------------- CSR build ----------------
__global__ void k_count(const int* __restrict__ dst, int* __restrict__ deg){
  int e = blockIdx.x*256 + threadIdx.x;
  if(e < NE){
    unsigned d = (unsigned)dst[e];
    if(d < NN) atomicAdd(&deg[d], 1);
  }
}

__global__ void k_scan(const int* __restrict__ deg, int* __restrict__ offp, int* __restrict__ cursor){
  __shared__ int part[256];
  __shared__ int excl[257];
  const int CH = (NN + 255)/256;
  int tid = threadIdx.x;
  int lo = tid*CH;
  int hi = lo + CH; if(hi > NN) hi = NN;
  int s = 0;
  for(int i=lo;i<hi;i++) s += deg[i];
  part[tid] = s;
  __syncthreads();
  if(tid == 0){
    int run = 0;
    for(int i=0;i<256;i++){ excl[i] = run; run += part[i]; }
    excl[256] = run;
  }
  __syncthreads();
  int run = excl[tid];
  for(int i=lo;i<hi;i++){ offp[i] = run; cursor[i] = run; run += deg[i]; }
  if(tid == 0) offp[NN] = excl[256];
}

__global__ void k_fill(const int* __restrict__ src, const int* __restrict__ dst,
                       int* __restrict__ cursor, int* __restrict__ csr_src){
  int e = blockIdx.x*256 + threadIdx.x;
  if(e >= NE) return;
  unsigned d = (unsigned)dst[e];
  if(d >= NN) return;
  unsigned p = (unsigned)atomicAdd(&cursor[d], 1);
  if(p < NE){
    unsigned sv = (unsigned)src[e];
    csr_src[p] = (sv < NN) ? (int)sv : 0;
  }
}

// ---------------- conversions / weight prep ----------------
__global__ void k_cvt_x(const void* __restrict__ x, const int* __restrict__ flag,
                        __hip_bfloat16* __restrict__ xb){
  int i = blockIdx.x*256 + threadIdx.x;
  int f = *flag;
  if(i < NN*256) xb[i] = f2bf(rdf(x, i, f));
}

__global__ void k_prep(const void* __restrict__ w_src, const void* __restrict__ w_dst,
                       const void* __restrict__ w_hh, const int* __restrict__ flag,
                       __hip_bfloat16* __restrict__ wsrcT, __hip_bfloat16* __restrict__ wdstT,
                       __hip_bfloat16* __restrict__ whhb){
  int tid = blockIdx.x*256 + threadIdx.x;
  int f = *flag;
  if(tid < 131072){
    int l = tid >> 16, r = tid & 65535, o = r >> 8, i = r & 255;
    wsrcT[tid] = f2bf(rdf(w_src, l*65536 + i*256 + o, f));
    wdstT[tid] = f2bf(rdf(w_dst, l*65536 + i*256 + o, f));
  }
  if(tid < 262144) whhb[tid] = f2bf(rdf(w_hh, tid, f));
}

// Wc[g,k] = sum_j Wih[g,j] * mlp_w[j, 1+k]
__global__ void k_prep_wc(const void* __restrict__ wih, const void* __restrict__ mlp_w,
                          const int* __restrict__ flag, __hip_bfloat16* __restrict__ Wc){
  int g = blockIdx.x;
  int k = threadIdx.x;
  int f = *flag;
  float s = 0.f;
  for(int j=0;j<256;j++) s += rdf(wih, g*256+j, f) * rdf(mlp_w, j*257 + 1 + k, f);
  Wc[g*256+k] = f2bf(s);
}

__global__ void k_prep_small(const void* __restrict__ wih, const void* __restrict__ mlp_w,
                             const void* __restrict__ mlp_b,
                             const void* __restrict__ b_ih, const void* __restrict__ b_hh,
                             const void* __restrict__ att, const void* __restrict__ gbias,
                             const void* __restrict__ init_w, const void* __restrict__ init_b,
                             const void* __restrict__ out_w, const void* __restrict__ out_b,
                             const int* __restrict__ flag,
                             float* __restrict__ u, float* __restrict__ bc,
                             float* __restrict__ attf, float* __restrict__ gbiasf,
                             float* __restrict__ initwf, float* __restrict__ outwf,
                             float* __restrict__ sc){
  int g = blockIdx.x*256 + threadIdx.x;
  int f = *flag;
  if(g < 1024){
    float su = 0.f, sb = 0.f;
    for(int j=0;j<256;j++){
      float w = rdf(wih, g*256+j, f);
      su += w * rdf(mlp_w, j*257, f);
      sb += w * rdf(mlp_b, j, f);
    }
    u[g] = su;
    bc[g] = sb + rdf(b_ih, g, f) + rdf(b_hh, g, f);
  }
  if(g < 512){ attf[g] = rdf(att, g, f); gbiasf[g] = rdf(gbias, g, f); }
  if(g < 256){ initwf[g] = rdf(init_w, g, f); outwf[g] = rdf(out_w, g, f); }
  if(g == 0){ sc[0] = rdf(init_b, 0, f); sc[1] = rdf(out_b, 0, f); }
}

// ---------------- NT GEMM (out-of-place): Q[m,n] = sum_k P[m,k]*B[n,k] ----------------
__global__ __launch_bounds__(256) void k_gemm_nt_bf(const __hip_bfloat16* __restrict__ A,
                                                    const __hip_bfloat16* __restrict__ B,
                                                    __hip_bfloat16* __restrict__ Cb){
  int wave = threadIdx.x >> 6;
  int lane = threadIdx.x & 63;
  int l16 = lane & 15, quad = lane >> 4, quad8 = quad*8;
  int mBase = blockIdx.x*64 + wave*16;
  int nBase = blockIdx.y*64;
  int arow = mBase + l16; if(arow >= NN) arow = NN-1;
  const __hip_bfloat16* aptr = A + (size_t)arow*256 + quad8;
  float4v acc[4];
  #pragma unroll
  for(int nt=0;nt<4;nt++){ acc[nt][0]=0.f; acc[nt][1]=0.f; acc[nt][2]=0.f; acc[nt][3]=0.f; }
  for(int k0=0;k0<256;k0+=32){
    bf16x8 a = LD8(aptr + k0);
    #pragma unroll
    for(int nt=0;nt<4;nt++){
      const __hip_bfloat16* bptr = B + (size_t)(nBase + nt*16 + l16)*256 + k0 + quad8;
      acc[nt] = MFMA16(a, LD8(bptr), acc[nt]);
    }
  }
  #pragma unroll
  for(int nt=0;nt<4;nt++){
    int col = nBase + nt*16 + l16;
    #pragma unroll
    for(int r=0;r<4;r++){
      int row = mBase + quad*4 + r;
      if(row < NN) Cb[(size_t)row*256 + col] = f2bf(acc[nt][r]);
    }
  }
}

// ---------------- in-place NT GEMM: P = P@B^T (LDS-staged A; row-exclusive blocks) ----
__global__ __launch_bounds__(256) void k_gemm_inplace(__hip_bfloat16* __restrict__ P,
                                                      const __hip_bfloat16* __restrict__ B){
  __shared__ __hip_bfloat16 sA[64*264];
  int tid = threadIdx.x;
  int mBase = blockIdx.x*64;
  {
    int r = tid >> 2;
    int c0 = (tid & 3)*64;
    int grow = mBase + r; if(grow >= NN) grow = NN-1;
    const __hip_bfloat16* srcp = P + (size_t)grow*256 + c0;
    #pragma unroll
    for(int j=0;j<8;j++) *(bf16x8*)(&sA[r*264 + c0 + j*8]) = LD8(srcp + j*8);
  }
  __syncthreads();
  int w = tid>>6, lane = tid&63, l16 = lane&15, quad = lane>>4, quad8 = quad*8;
  const __hip_bfloat16* arow = &sA[(w*16 + l16)*264 + quad8];
  float4v acc[16];
  #pragma unroll
  for(int nt=0;nt<16;nt++){ acc[nt][0]=0.f; acc[nt][1]=0.f; acc[nt][2]=0.f; acc[nt][3]=0.f; }
  for(int k0=0;k0<256;k0+=32){
    bf16x8 a = *(const bf16x8*)(arow + k0);
    #pragma unroll
    for(int nt=0;nt<16;nt++)
      acc[nt] = MFMA16(a, LD8(B + (size_t)(nt*16+l16)*256 + k0 + quad8), acc[nt]);
  }
  #pragma unroll
  for(int nt=0;nt<16;nt++){
    int col = nt*16 + l16;
    #pragma unroll
    for(int r=0;r<4;r++){
      int row = mBase + w*16 + quad*4 + r;
      if(row < NN) P[(size_t)row*256 + col] = f2bf(acc[nt][r]);
    }
  }
}

// ---------------- fused GAT edge phase: logits+softmax+aggregate+ELU (per node) ------
__global__ __launch_bounds__(256) void k_node_fused(const __hip_bfloat16* __restrict__ Q,
                                                    __hip_bfloat16* __restrict__ P,
                                                    const int* __restrict__ offp,
                                                    const int* __restrict__ csr_src,
                                                    const float* __restrict__ attf,
                                                    const float* __restrict__ gbiasf){
  __shared__ float slog[DEGMAX*4];
  __shared__ int ssrc[DEGMAX];
  int node = blockIdx.x;
  int tid = threadIdx.x;
  int s0 = offp[node], s1 = offp[node+1];
  if(s0 < 0) s0 = 0; if(s0 > NE) s0 = NE;
  if(s1 < s0) s1 = s0; if(s1 > NE) s1 = NE;
  int deg = s1 - s0; if(deg > DEGMAX) deg = DEGMAX;
  if(tid < deg){
    unsigned sv = (unsigned)csr_src[s0 + tid];
    ssrc[tid] = (sv < NN) ? (int)sv : 0;
  }
  __syncthreads();
  int w = tid>>6, lane = tid&63;
  for(int idx=w; idx<deg; idx+=4){
    const __hip_bfloat16* pl = Q + (size_t)ssrc[idx]*256;
    const __hip_bfloat16* pr = P + (size_t)node*256;
    float a[4];
    #pragma unroll
    for(int h=0;h<4;h++){
      float v = bf2f(pl[h*64+lane]) + bf2f(pr[h*64+lane]);
      v = (v > 0.f) ? v : 0.2f*v;
      a[h] = v * attf[h*64+lane];
    }
    #pragma unroll
    for(int h=0;h<4;h++){
      float s = a[h];
      s += __shfl_xor(s, 1, 64);
      s += __shfl_xor(s, 2, 64);
      s += __shfl_xor(s, 4, 64);
      s += __shfl_xor(s, 8, 64);
      s += __shfl_xor(s, 16, 64);
      s += __shfl_xor(s, 32, 64);
      if(lane == 0) slog[idx*4 + h] = s;
    }
  }
  __syncthreads();
  if(tid < 4){
    int h = tid;
    float m = -1e30f;
    for(int i=0;i<deg;i++) m = fmaxf(m, slog[i*4+h]);
    float den = 0.f;
    for(int i=0;i<deg;i++) den += __expf(slog[i*4+h] - m);
    float inv = (den > 0.f) ? 1.f/den : 0.f;
    for(int i=0;i<deg;i++) slog[i*4+h] = __expf(slog[i*4+h] - m)*inv;
  }
  __syncthreads();
  int d = tid, h = d>>6;
  float acc = 0.f;
  for(int i=0;i<deg;i++) acc += slog[i*4+h] * bf2f(Q[(size_t)ssrc[i]*256 + d]);
  acc += gbiasf[d];
  acc = (acc > 0.f) ? acc : (__expf(acc) - 1.f);   // ELU
  P[(size_t)node*256 + d] = f2bf(acc);
}

// ---------------- persistent LSTM: 16 rows/block, all 12 steps in one launch ---------
// GX = ctx@Wc^T + bc computed ONCE into MFMA-accumulator-layout registers (gxr);
// each step's gates GEMM starts from acc = gxr (C-input of the MFMA chain), so
// gates = GX + h@Whh^T with no LDS sgx and no global GX stream.
// LDS 41.3 KB -> 3 blocks/CU; __launch_bounds__(256,3) caps VGPR at 170.
__global__ __launch_bounds__(256, 3) void k_lstm12(const __hip_bfloat16* __restrict__ ctx,
                                                   const __hip_bfloat16* __restrict__ Wc,
                                                   const __hip_bfloat16* __restrict__ Whh,
                                                   const float* __restrict__ u_vec,
                                                   const float* __restrict__ bc_vec,
                                                   const float* __restrict__ initwf,
                                                   const float* __restrict__ outwf,
                                                   const float* __restrict__ sc,
                                                   float* __restrict__ out){
  __shared__ __hip_bfloat16 sg[4*16*256];   // 32KB: all 4 gates, 16 rows, 256 cols
  __shared__ __hip_bfloat16 sh[16*264];     // h tile (bank-padded)
  __shared__ float spart[256];
  __shared__ float sprev[16];
  int tid = threadIdx.x;
  int mBase = blockIdx.x*16;               // 1250*16 == NN exactly
  int w = tid>>6, lane = tid&63, l16 = lane&15, quad = lane>>4, quad8 = quad*8;
  // h0 = ctx rows
  {
    int r = tid >> 4, c0 = (tid & 15)*16;
    const __hip_bfloat16* srcp = ctx + (size_t)(mBase + r)*256 + c0;
    *(bf16x8*)(&sh[r*264 + c0])     = LD8(srcp);
    *(bf16x8*)(&sh[r*264 + c0 + 8]) = LD8(srcp + 8);
  }
  __syncthreads();
  // prev0 = ctx @ init_w + init_b
  {
    int r = tid >> 4, c0 = (tid & 15)*16;
    float part = 0.f;
    #pragma unroll
    for(int j=0;j<16;j++) part += bf2f(sh[r*264 + c0 + j]) * initwf[c0 + j];
    spart[tid] = part;
  }
  __syncthreads();
  if(tid < 16){
    float s = 0.f;
    #pragma unroll
    for(int j=0;j<16;j++) s += spart[tid*16 + j];
    sprev[tid] = s + sc[0];
  }
  __syncthreads();
  // GX phase: gxr[nt] = (ctx @ Wc^T)[16x256 tile of gate w] + bc  (C-layout registers)
  float4v gxr[16];
  {
    #pragma unroll
    for(int nt=0;nt<16;nt++){ gxr[nt][0]=0.f; gxr[nt][1]=0.f; gxr[nt][2]=0.f; gxr[nt][3]=0.f; }
    const __hip_bfloat16* Wcb = Wc + ((size_t)(w*256 + l16))*256 + quad8;
    for(int k0=0;k0<256;k0+=32){
      bf16x8 a = *(const bf16x8*)(&sh[l16*264 + k0 + quad8]);
      #pragma unroll
      for(int nt=0;nt<16;nt++)
        gxr[nt] = MFMA16(a, LD8(Wcb + nt*4096 + k0), gxr[nt]);
    }
    #pragma unroll
    for(int nt=0;nt<16;nt++){
      float bcv = bc_vec[w*256 + nt*16 + l16];
      #pragma unroll
      for(int r=0;r<4;r++) gxr[nt][r] += bcv;
    }
  }
  float creg[16];
  #pragma unroll
  for(int i=0;i<16;i++) creg[i] = 0.f;
  float uw0 = u_vec[tid], uw1 = u_vec[256+tid], uw2 = u_vec[512+tid], uw3 = u_vec[768+tid];
  float ow = outwf[tid];
  float outb = sc[1];
  const __hip_bfloat16* Wbase = Whh + ((size_t)(w*256 + l16))*256 + quad8;
  for(int step=0; step<TOUT; step++){
    // (a) gates GEMM seeded with GX: acc = gxr + h@Whh^T
    float4v acc[16];
    #pragma unroll
    for(int nt=0;nt<16;nt++) acc[nt] = gxr[nt];
    for(int k0=0;k0<256;k0+=32){
      bf16x8 a = *(const bf16x8*)(&sh[l16*264 + k0 + quad8]);
      #pragma unroll
      for(int nt=0;nt<16;nt++)
        acc[nt] = MFMA16(a, LD8(Wbase + nt*4096 + k0), acc[nt]);
    }
    // (b) write C tiles to sg
    #pragma unroll
    for(int nt=0;nt<16;nt++){
      int col = nt*16 + l16;
      #pragma unroll
      for(int r=0;r<4;r++)
        sg[w*4096 + (quad*4 + r)*256 + col] = f2bf(acc[nt][r]);
    }
    __syncthreads();   // (c)
    // (d) activation: thread = col, 16 rows
    #pragma unroll
    for(int i=0;i<16;i++){
      float p = sprev[i];
      float g0 = bf2f(sg[         i*256 + tid]) + p*uw0;
      float g1 = bf2f(sg[ 4096 +  i*256 + tid]) + p*uw1;
      float g2 = bf2f(sg[ 8192 +  i*256 + tid]) + p*uw2;
      float g3 = bf2f(sg[12288 +  i*256 + tid]) + p*uw3;
      float iv = sigmoidf_(g0), fv = sigmoidf_(g1);
      float gv = tanhf(g2),     ov = sigmoidf_(g3);
      float cn = fv*creg[i] + iv*gv;
      creg[i] = cn;
      sh[i*264 + tid] = f2bf(ov * tanhf(cn));
    }
    __syncthreads();   // (e) h visible
    // prev_{t+1} = h @ out_w + out_b; out[:, step]
    {
      int r = tid >> 4, c0 = (tid & 15)*16;
      float part = 0.f;
      #pragma unroll
      for(int j=0;j<16;j++) part += bf2f(sh[r*264 + c0 + j]) * outwf[c0 + j];
      spart[tid] = part;
    }
    __syncthreads();   // (e2) spart visible
    if(tid < 16){
      float s = 0.f;
      #pragma unroll
      for(int j=0;j<16;j++) s += spart[tid*16 + j];
      s += outb;
      sprev[tid] = s;
      out[(size_t)(mBase + tid)*TOUT + step] = s;
    }
    // next (c) barrier covers sprev/sg hazards
  }
}

// ---------------- launch ----------------
extern "C" void kernel_launch(void* const* d_in, const int* in_sizes, int n_in,
                              void* d_out, int out_size, void* d_ws, size_t ws_size,
                              hipStream_t stream){
  const void* x      = d_in[0];
  const int*  ei     = (const int*)d_in[1];
  const void* w_src  = d_in[2];
  const void* w_dst  = d_in[3];
  const void* att    = d_in[4];
  const void* gbias  = d_in[5];
  const void* mlp_w  = d_in[6];
  const void* mlp_b  = d_in[7];
  const void* w_ih   = d_in[8];
  const void* w_hh   = d_in[9];
  const void* b_ih   = d_in[10];
  const void* b_hh   = d_in[11];
  const void* init_w = d_in[12];
  const void* init_b = d_in[13];
  const void* out_w  = d_in[14];
  const void* out_b  = d_in[15];
  float* out = (float*)d_out;
  const int* srcp = ei;
  const int* dstp = ei + NE;
  (void)in_sizes; (void)n_in;

  char* ws = (char*)d_ws;
  size_t off = 0;
  auto alloc = [&](size_t bytes)->void*{
    void* p = ws + off;
    off += (bytes + 255) & ~(size_t)255;
    return p;
  };
  __hip_bfloat16* P = (__hip_bfloat16*)alloc((size_t)NN*256*2);  // x -> xr -> layer out -> ctx
  __hip_bfloat16* Q = (__hip_bfloat16*)alloc((size_t)NN*256*2);  // xl per layer
  int* deg      = (int*)alloc((size_t)NN*4);
  int* offp     = (int*)alloc((size_t)(NN+1)*4);
  int* cursor   = (int*)alloc((size_t)NN*4);
  int* csr_src  = (int*)alloc((size_t)NE*4);
  __hip_bfloat16* wsrcT = (__hip_bfloat16*)alloc((size_t)131072*2);
  __hip_bfloat16* wdstT = (__hip_bfloat16*)alloc((size_t)131072*2);
  __hip_bfloat16* whhb  = (__hip_bfloat16*)alloc((size_t)262144*2);
  __hip_bfloat16* Wc    = (__hip_bfloat16*)alloc((size_t)262144*2);
  float* u_vec  = (float*)alloc(1024*4);
  float* bc_vec = (float*)alloc(1024*4);
  float* attf   = (float*)alloc(512*4);
  float* gbiasf = (float*)alloc(512*4);
  float* initwf = (float*)alloc(256*4);
  float* outwf  = (float*)alloc(256*4);
  float* sc     = (float*)alloc(2*4);
  int*   flag   = (int*)alloc(4);
  // total ~23.6 MB

  if(off > ws_size){
    k_fail<<<(out_size + 255)/256, 256, 0, stream>>>(out, out_size);
    return;
  }

  // dtype detect + CSR + prep
  k_detect<<<1, 256, 0, stream>>>(x, flag);
  hipMemsetAsync(deg, 0, (size_t)NN*4, stream);
  hipMemsetAsync(csr_src, 0xFF, (size_t)NE*4, stream);
  k_count<<<NE/256, 256, 0, stream>>>(dstp, deg);
  k_scan<<<1, 256, 0, stream>>>(deg, offp, cursor);
  k_fill<<<NE/256, 256, 0, stream>>>(srcp, dstp, cursor, csr_src);
  k_cvt_x<<<NN, 256, 0, stream>>>(x, flag, P);
  k_prep<<<1024, 256, 0, stream>>>(w_src, w_dst, w_hh, flag, wsrcT, wdstT, whhb);
  k_prep_wc<<<1024, 256, 0, stream>>>(w_ih, mlp_w, flag, Wc);
  k_prep_small<<<4, 256, 0, stream>>>(w_ih, mlp_w, mlp_b, b_ih, b_hh, att, gbias,
                                      init_w, init_b, out_w, out_b, flag,
                                      u_vec, bc_vec, attf, gbiasf, initwf, outwf, sc);

  // GAT layers: Q = P@Wsrc^T (xl); P = P@Wdst^T in-place (xr); fused edge phase -> P
  dim3 g64(313, 4);
  for(int l=0;l<2;l++){
    k_gemm_nt_bf<<<g64, 256, 0, stream>>>(P, wsrcT + l*65536, Q);
    k_gemm_inplace<<<313, 256, 0, stream>>>(P, wdstT + l*65536);
    k_node_fused<<<NN, 256, 0, stream>>>(Q, P, offp, csr_src, attf + l*256, gbiasf + l*256);
  }

  // persistent LSTM decoder: GX carried in accumulator registers
  k_lstm12<<<1250, 256, 0, stream>>>(P, Wc, whhb, u_vec, bc_vec, initwf, outwf, sc, out);
}

// Round 10
// 2716.758 us; speedup vs baseline: 1.2061x; 1.1000x over previous
//
#include <hip/hip_runtime.h>
#include <hip/hip_bf16.h>

#define NN 20000
#define NE 320000
#define TOUT 12
#define DEGMAX 96
#define SGXP 1028   // sgx row stride (bf16): 1028/2=514 dwords == 2 mod 8 -> quads hit banks 0/8/16/24

typedef __bf16 bf16x8 __attribute__((ext_vector_type(8)));
typedef float float4v __attribute__((ext_vector_type(4)));

#define LD8(p) (*(const bf16x8*)(p))
#define MFMA16(a,b,c) __builtin_amdgcn_mfma_f32_16x16x32_bf16((a),(b),(c),0,0,0)

__device__ __forceinline__ float bf2f(const __hip_bfloat16 v){ return __bfloat162float(v); }
__device__ __forceinline__ __hip_bfloat16 f2bf(float v){ return __float2bfloat16(v); }
__device__ __forceinline__ float sigmoidf_(float x){ return 1.0f/(1.0f + __expf(-x)); }
__device__ __forceinline__ float rdf(const void* p, int i, int f32){
  return f32 ? ((const float*)p)[i] : __bfloat162float(((const __hip_bfloat16*)p)[i]);
}

// ---------------- input dtype detector ----------------
__global__ void k_detect(const void* xraw, int* flag){
  __shared__ int cnt;
  if(threadIdx.x == 0) cnt = 0;
  __syncthreads();
  const unsigned* w = (const unsigned*)xraw;
  int local = 0;
  for(int i = threadIdx.x; i < 4096; i += 256){
    unsigned b = (w[i] >> 8) & 0x7F;
    if(b >= 0x33 && b <= 0x3F) local++;
  }
  atomicAdd(&cnt, local);
  __syncthreads();
  if(threadIdx.x == 0) *flag = (cnt > 2048) ? 0 : 1;   // 1 => fp32 inputs
}

// guard signature: constant 256.0 everywhere (fp32 out)
__global__ void k_fail(float* out, int n){
  int i = blockIdx.x*256 + threadIdx.x;
  if(i < n) out[i] = 256.0f;
}

// ---------------- CSR build ----------------
__global__ void k_count(const int* __restrict__ dst, int* __restrict__ deg){
  int e = blockIdx.x*256 + threadIdx.x;
  if(e < NE){
    unsigned d = (unsigned)dst[e];
    if(d < NN) atomicAdd(&deg[d], 1);
  }
}

__global__ void k_scan(const int* __restrict__ deg, int* __restrict__ offp, int* __restrict__ cursor){
  __shared__ int part[256];
  __shared__ int excl[257];
  const int CH = (NN + 255)/256;
  int tid = threadIdx.x;
  int lo = tid*CH;
  int hi = lo + CH; if(hi > NN) hi = NN;
  int s = 0;
  for(int i=lo;i<hi;i++) s += deg[i];
  part[tid] = s;
  __syncthreads();
  if(tid == 0){
    int run = 0;
    for(int i=0;i<256;i++){ excl[i] = run; run += part[i]; }
    excl[256] = run;
  }
  __syncthreads();
  int run = excl[tid];
  for(int i=lo;i<hi;i++){ offp[i] = run; cursor[i] = run; run += deg[i]; }
  if(tid == 0) offp[NN] = excl[256];
}

__global__ void k_fill(const int* __restrict__ src, const int* __restrict__ dst,
                       int* __restrict__ cursor, int* __restrict__ csr_src){
  int e = blockIdx.x*256 + threadIdx.x;
  if(e >= NE) return;
  unsigned d = (unsigned)dst[e];
  if(d >= NN) return;
  unsigned p = (unsigned)atomicAdd(&cursor[d], 1);
  if(p < NE){
    unsigned sv = (unsigned)src[e];
    csr_src[p] = (sv < NN) ? (int)sv : 0;
  }
}

// ---------------- conversions / weight prep ----------------
__global__ void k_cvt_x(const void* __restrict__ x, const int* __restrict__ flag,
                        __hip_bfloat16* __restrict__ xb){
  int i = blockIdx.x*256 + threadIdx.x;
  int f = *flag;
  if(i < NN*256) xb[i] = f2bf(rdf(x, i, f));
}

__global__ void k_prep(const void* __restrict__ w_src, const void* __restrict__ w_dst,
                       const void* __restrict__ w_hh, const int* __restrict__ flag,
                       __hip_bfloat16* __restrict__ wsrcT, __hip_bfloat16* __restrict__ wdstT,
                       __hip_bfloat16* __restrict__ whhb){
  int tid = blockIdx.x*256 + threadIdx.x;
  int f = *flag;
  if(tid < 131072){
    int l = tid >> 16, r = tid & 65535, o = r >> 8, i = r & 255;
    wsrcT[tid] = f2bf(rdf(w_src, l*65536 + i*256 + o, f));
    wdstT[tid] = f2bf(rdf(w_dst, l*65536 + i*256 + o, f));
  }
  if(tid < 262144) whhb[tid] = f2bf(rdf(w_hh, tid, f));
}

// Wc[g,k] = sum_j Wih[g,j] * mlp_w[j, 1+k]
__global__ void k_prep_wc(const void* __restrict__ wih, const void* __restrict__ mlp_w,
                          const int* __restrict__ flag, __hip_bfloat16* __restrict__ Wc){
  int g = blockIdx.x;
  int k = threadIdx.x;
  int f = *flag;
  float s = 0.f;
  for(int j=0;j<256;j++) s += rdf(wih, g*256+j, f) * rdf(mlp_w, j*257 + 1 + k, f);
  Wc[g*256+k] = f2bf(s);
}

__global__ void k_prep_small(const void* __restrict__ wih, const void* __restrict__ mlp_w,
                             const void* __restrict__ mlp_b,
                             const void* __restrict__ b_ih, const void* __restrict__ b_hh,
                             const void* __restrict__ att, const void* __restrict__ gbias,
                             const void* __restrict__ init_w, const void* __restrict__ init_b,
                             const void* __restrict__ out_w, const void* __restrict__ out_b,
                             const int* __restrict__ flag,
                             float* __restrict__ u, float* __restrict__ bc,
                             float* __restrict__ attf, float* __restrict__ gbiasf,
                             float* __restrict__ initwf, float* __restrict__ outwf,
                             float* __restrict__ sc){
  int g = blockIdx.x*256 + threadIdx.x;
  int f = *flag;
  if(g < 1024){
    float su = 0.f, sb = 0.f;
    for(int j=0;j<256;j++){
      float w = rdf(wih, g*256+j, f);
      su += w * rdf(mlp_w, j*257, f);
      sb += w * rdf(mlp_b, j, f);
    }
    u[g] = su;
    bc[g] = sb + rdf(b_ih, g, f) + rdf(b_hh, g, f);
  }
  if(g < 512){ attf[g] = rdf(att, g, f); gbiasf[g] = rdf(gbias, g, f); }
  if(g < 256){ initwf[g] = rdf(init_w, g, f); outwf[g] = rdf(out_w, g, f); }
  if(g == 0){ sc[0] = rdf(init_b, 0, f); sc[1] = rdf(out_b, 0, f); }
}

// ---------------- NT GEMM (out-of-place): Q[m,n] = sum_k P[m,k]*B[n,k] ----------------
__global__ __launch_bounds__(256) void k_gemm_nt_bf(const __hip_bfloat16* __restrict__ A,
                                                    const __hip_bfloat16* __restrict__ B,
                                                    __hip_bfloat16* __restrict__ Cb){
  int wave = threadIdx.x >> 6;
  int lane = threadIdx.x & 63;
  int l16 = lane & 15, quad = lane >> 4, quad8 = quad*8;
  int mBase = blockIdx.x*64 + wave*16;
  int nBase = blockIdx.y*64;
  int arow = mBase + l16; if(arow >= NN) arow = NN-1;
  const __hip_bfloat16* aptr = A + (size_t)arow*256 + quad8;
  float4v acc[4];
  #pragma unroll
  for(int nt=0;nt<4;nt++){ acc[nt][0]=0.f; acc[nt][1]=0.f; acc[nt][2]=0.f; acc[nt][3]=0.f; }
  for(int k0=0;k0<256;k0+=32){
    bf16x8 a = LD8(aptr + k0);
    #pragma unroll
    for(int nt=0;nt<4;nt++){
      const __hip_bfloat16* bptr = B + (size_t)(nBase + nt*16 + l16)*256 + k0 + quad8;
      acc[nt] = MFMA16(a, LD8(bptr), acc[nt]);
    }
  }
  #pragma unroll
  for(int nt=0;nt<4;nt++){
    int col = nBase + nt*16 + l16;
    #pragma unroll
    for(int r=0;r<4;r++){
      int row = mBase + quad*4 + r;
      if(row < NN) Cb[(size_t)row*256 + col] = f2bf(acc[nt][r]);
    }
  }
}

// ---------------- in-place NT GEMM: P = P@B^T (LDS-staged A; row-exclusive blocks) ----
__global__ __launch_bounds__(256) void k_gemm_inplace(__hip_bfloat16* __restrict__ P,
                                                      const __hip_bfloat16* __restrict__ B){
  __shared__ __hip_bfloat16 sA[64*264];
  int tid = threadIdx.x;
  int mBase = blockIdx.x*64;
  {
    int r = tid >> 2;
    int c0 = (tid & 3)*64;
    int grow = mBase + r; if(grow >= NN) grow = NN-1;
    const __hip_bfloat16* srcp = P + (size_t)grow*256 + c0;
    #pragma unroll
    for(int j=0;j<8;j++) *(bf16x8*)(&sA[r*264 + c0 + j*8]) = LD8(srcp + j*8);
  }
  __syncthreads();
  int w = tid>>6, lane = tid&63, l16 = lane&15, quad = lane>>4, quad8 = quad*8;
  const __hip_bfloat16* arow = &sA[(w*16 + l16)*264 + quad8];
  float4v acc[16];
  #pragma unroll
  for(int nt=0;nt<16;nt++){ acc[nt][0]=0.f; acc[nt][1]=0.f; acc[nt][2]=0.f; acc[nt][3]=0.f; }
  for(int k0=0;k0<256;k0+=32){
    bf16x8 a = *(const bf16x8*)(arow + k0);
    #pragma unroll
    for(int nt=0;nt<16;nt++)
      acc[nt] = MFMA16(a, LD8(B + (size_t)(nt*16+l16)*256 + k0 + quad8), acc[nt]);
  }
  #pragma unroll
  for(int nt=0;nt<16;nt++){
    int col = nt*16 + l16;
    #pragma unroll
    for(int r=0;r<4;r++){
      int row = mBase + w*16 + quad*4 + r;
      if(row < NN) P[(size_t)row*256 + col] = f2bf(acc[nt][r]);
    }
  }
}

// ---------------- fused GAT edge phase: logits+softmax+aggregate+ELU (per node) ------
__global__ __launch_bounds__(256) void k_node_fused(const __hip_bfloat16* __restrict__ Q,
                                                    __hip_bfloat16* __restrict__ P,
                                                    const int* __restrict__ offp,
                                                    const int* __restrict__ csr_src,
                                                    const float* __restrict__ attf,
                                                    const float* __restrict__ gbiasf){
  __shared__ float slog[DEGMAX*4];
  __shared__ int ssrc[DEGMAX];
  int node = blockIdx.x;
  int tid = threadIdx.x;
  int s0 = offp[node], s1 = offp[node+1];
  if(s0 < 0) s0 = 0; if(s0 > NE) s0 = NE;
  if(s1 < s0) s1 = s0; if(s1 > NE) s1 = NE;
  int deg = s1 - s0; if(deg > DEGMAX) deg = DEGMAX;
  if(tid < deg){
    unsigned sv = (unsigned)csr_src[s0 + tid];
    ssrc[tid] = (sv < NN) ? (int)sv : 0;
  }
  __syncthreads();
  int w = tid>>6, lane = tid&63;
  for(int idx=w; idx<deg; idx+=4){
    const __hip_bfloat16* pl = Q + (size_t)ssrc[idx]*256;
    const __hip_bfloat16* pr = P + (size_t)node*256;
    float a[4];
    #pragma unroll
    for(int h=0;h<4;h++){
      float v = bf2f(pl[h*64+lane]) + bf2f(pr[h*64+lane]);
      v = (v > 0.f) ? v : 0.2f*v;
      a[h] = v * attf[h*64+lane];
    }
    #pragma unroll
    for(int h=0;h<4;h++){
      float s = a[h];
      s += __shfl_xor(s, 1, 64);
      s += __shfl_xor(s, 2, 64);
      s += __shfl_xor(s, 4, 64);
      s += __shfl_xor(s, 8, 64);
      s += __shfl_xor(s, 16, 64);
      s += __shfl_xor(s, 32, 64);
      if(lane == 0) slog[idx*4 + h] = s;
    }
  }
  __syncthreads();
  if(tid < 4){
    int h = tid;
    float m = -1e30f;
    for(int i=0;i<deg;i++) m = fmaxf(m, slog[i*4+h]);
    float den = 0.f;
    for(int i=0;i<deg;i++) den += __expf(slog[i*4+h] - m);
    float inv = (den > 0.f) ? 1.f/den : 0.f;
    for(int i=0;i<deg;i++) slog[i*4+h] = __expf(slog[i*4+h] - m)*inv;
  }
  __syncthreads();
  int d = tid, h = d>>6;
  float acc = 0.f;
  for(int i=0;i<deg;i++) acc += slog[i*4+h] * bf2f(Q[(size_t)ssrc[i]*256 + d]);
  acc += gbiasf[d];
  acc = (acc > 0.f) ? acc : (__expf(acc) - 1.f);   // ELU
  P[(size_t)node*256 + d] = f2bf(acc);
}

// ---------------- persistent LSTM: 16 rows/block, all 12 steps in one launch ---------
// Decomposition: wave w owns cols [w*64,(w+1)*64) for ALL 4 gates -> nt = g*4+t.
// For fixed (row,col) all 4 gates land in the same lane's accumulators -> activation
// is fully in-register (no gate-exchange LDS). GX = ctx@Wc^T + bc in LDS (computed
// once via MFMA). LDS ~42.7 KB -> 3 blocks/CU; regs ~120 < 170 cap -> no spill.
__global__ __launch_bounds__(256, 3) void k_lstm12(const __hip_bfloat16* __restrict__ ctx,
                                                   const __hip_bfloat16* __restrict__ Wc,
                                                   const __hip_bfloat16* __restrict__ Whh,
                                                   const float* __restrict__ u_vec,
                                                   const float* __restrict__ bc_vec,
                                                   const float* __restrict__ initwf,
                                                   const float* __restrict__ outwf,
                                                   const float* __restrict__ sc,
                                                   float* __restrict__ out){
  __shared__ __hip_bfloat16 sgx[16*SGXP];    // 32.9KB: GX+bc, [row][gatecol]
  __shared__ __hip_bfloat16 sh[16*264];      // h tile (bank-padded)
  __shared__ float spart[256];               // init-reduction scratch
  __shared__ float spartw[64];               // per-wave out-projection partials
  __shared__ float sprev[16];
  int tid = threadIdx.x;
  int mBase = blockIdx.x*16;                 // 1250*16 == NN exactly
  int w = tid>>6, lane = tid&63, l16 = lane&15, quad = lane>>4, quad8 = quad*8;
  // h0 = ctx rows
  {
    int r = tid >> 4, c0 = (tid & 15)*16;
    const __hip_bfloat16* srcp = ctx + (size_t)(mBase + r)*256 + c0;
    *(bf16x8*)(&sh[r*264 + c0])     = LD8(srcp);
    *(bf16x8*)(&sh[r*264 + c0 + 8]) = LD8(srcp + 8);
  }
  __syncthreads();
  // prev0 = ctx @ init_w + init_b
  {
    int r = tid >> 4, c0 = (tid & 15)*16;
    float part = 0.f;
    #pragma unroll
    for(int j=0;j<16;j++) part += bf2f(sh[r*264 + c0 + j]) * initwf[c0 + j];
    spart[tid] = part;
  }
  __syncthreads();
  if(tid < 16){
    float s = 0.f;
    #pragma unroll
    for(int j=0;j<16;j++) s += spart[tid*16 + j];
    sprev[tid] = s + sc[0];
  }
  // per-thread constants
  float ureg[16], owreg[4];
  #pragma unroll
  for(int g=0;g<4;g++)
    #pragma unroll
    for(int t=0;t<4;t++) ureg[g*4+t] = u_vec[g*256 + w*64 + t*16 + l16];
  #pragma unroll
  for(int t=0;t<4;t++) owreg[t] = outwf[w*64 + t*16 + l16];
  float outb = sc[1];
  // GX phase: acc = ctx@Wc^T (this wave's 4-gate 64-col slab), +bc, -> sgx
  {
    float4v acc[16];
    #pragma unroll
    for(int nt=0;nt<16;nt++){ acc[nt][0]=0.f; acc[nt][1]=0.f; acc[nt][2]=0.f; acc[nt][3]=0.f; }
    for(int k0=0;k0<256;k0+=32){
      bf16x8 a = *(const bf16x8*)(&sh[l16*264 + k0 + quad8]);
      #pragma unroll
      for(int nt=0;nt<16;nt++){
        int brow = (nt>>2)*256 + w*64 + (nt&3)*16 + l16;
        acc[nt] = MFMA16(a, LD8(Wc + (size_t)brow*256 + k0 + quad8), acc[nt]);
      }
    }
    #pragma unroll
    for(int nt=0;nt<16;nt++){
      int gc = (nt>>2)*256 + w*64 + (nt&3)*16 + l16;
      float bcv = bc_vec[gc];
      #pragma unroll
      for(int r=0;r<4;r++)
        sgx[(quad*4 + r)*SGXP + gc] = f2bf(acc[nt][r] + bcv);
    }
  }
  __syncthreads();   // sgx + sprev visible
  float creg[16];
  #pragma unroll
  for(int i=0;i<16;i++) creg[i] = 0.f;
  for(int step=0; step<TOUT; step++){
    // (a) gates GEMM: acc[g*4+t] = h @ Whh^T slab
    float4v acc[16];
    #pragma unroll
    for(int nt=0;nt<16;nt++){ acc[nt][0]=0.f; acc[nt][1]=0.f; acc[nt][2]=0.f; acc[nt][3]=0.f; }
    for(int k0=0;k0<256;k0+=32){
      bf16x8 a = *(const bf16x8*)(&sh[l16*264 + k0 + quad8]);
      #pragma unroll
      for(int nt=0;nt<16;nt++){
        int brow = (nt>>2)*256 + w*64 + (nt&3)*16 + l16;
        acc[nt] = MFMA16(a, LD8(Whh + (size_t)brow*256 + k0 + quad8), acc[nt]);
      }
    }
    __syncthreads();   // S1: all sh reads done; sprev (from prev step) visible
    // (b) in-register activation + h write + out-projection partials
    float hsum[4] = {0.f, 0.f, 0.f, 0.f};
    #pragma unroll
    for(int t=0;t<4;t++){
      int col = w*64 + t*16 + l16;
      #pragma unroll
      for(int r=0;r<4;r++){
        int row = quad*4 + r;
        float p = sprev[row];
        float g0 = acc[t][r]      + bf2f(sgx[row*SGXP + col])       + p*ureg[t];
        float g1 = acc[4+t][r]    + bf2f(sgx[row*SGXP + 256 + col]) + p*ureg[4+t];
        float g2 = acc[8+t][r]    + bf2f(sgx[row*SGXP + 512 + col]) + p*ureg[8+t];
        float g3 = acc[12+t][r]   + bf2f(sgx[row*SGXP + 768 + col]) + p*ureg[12+t];
        float iv = sigmoidf_(g0), fv = sigmoidf_(g1);
        float gv = tanhf(g2),     ov = sigmoidf_(g3);
        float cn = fv*creg[t*4+r] + iv*gv;
        creg[t*4+r] = cn;
        float hn = ov * tanhf(cn);
        sh[row*264 + col] = f2bf(hn);
        hsum[r] += hn * owreg[t];
      }
    }
    #pragma unroll
    for(int r=0;r<4;r++){
      hsum[r] += __shfl_xor(hsum[r], 1, 64);
      hsum[r] += __shfl_xor(hsum[r], 2, 64);
      hsum[r] += __shfl_xor(hsum[r], 4, 64);
      hsum[r] += __shfl_xor(hsum[r], 8, 64);
    }
    if(l16 == 0){
      #pragma unroll
      for(int r=0;r<4;r++) spartw[w*16 + quad*4 + r] = hsum[r];
    }
    __syncthreads();   // S2: sh writes + spartw visible
    if(tid < 16){
      float s = spartw[tid] + spartw[16+tid] + spartw[32+tid] + spartw[48+tid] + outb;
      sprev[tid] = s;
      out[(size_t)(mBase + tid)*TOUT + step] = s;
    }
    // next S1 makes sprev visible before next activation
  }
}

// ---------------- launch ----------------
extern "C" void kernel_launch(void* const* d_in, const int* in_sizes, int n_in,
                              void* d_out, int out_size, void* d_ws, size_t ws_size,
                              hipStream_t stream){
  const void* x      = d_in[0];
  const int*  ei     = (const int*)d_in[1];
  const void* w_src  = d_in[2];
  const void* w_dst  = d_in[3];
  const void* att    = d_in[4];
  const void* gbias  = d_in[5];
  const void* mlp_w  = d_in[6];
  const void* mlp_b  = d_in[7];
  const void* w_ih   = d_in[8];
  const void* w_hh   = d_in[9];
  const void* b_ih   = d_in[10];
  const void* b_hh   = d_in[11];
  const void* init_w = d_in[12];
  const void* init_b = d_in[13];
  const void* out_w  = d_in[14];
  const void* out_b  = d_in[15];
  float* out = (float*)d_out;
  const int* srcp = ei;
  const int* dstp = ei + NE;
  (void)in_sizes; (void)n_in;

  char* ws = (char*)d_ws;
  size_t off = 0;
  auto alloc = [&](size_t bytes)->void*{
    void* p = ws + off;
    off += (bytes + 255) & ~(size_t)255;
    return p;
  };
  __hip_bfloat16* P = (__hip_bfloat16*)alloc((size_t)NN*256*2);  // x -> xr -> layer out -> ctx
  __hip_bfloat16* Q = (__hip_bfloat16*)alloc((size_t)NN*256*2);  // xl per layer
  int* deg      = (int*)alloc((size_t)NN*4);
  int* offp     = (int*)alloc((size_t)(NN+1)*4);
  int* cursor   = (int*)alloc((size_t)NN*4);
  int* csr_src  = (int*)alloc((size_t)NE*4);
  __hip_bfloat16* wsrcT = (__hip_bfloat16*)alloc((size_t)131072*2);
  __hip_bfloat16* wdstT = (__hip_bfloat16*)alloc((size_t)131072*2);
  __hip_bfloat16* whhb  = (__hip_bfloat16*)alloc((size_t)262144*2);
  __hip_bfloat16* Wc    = (__hip_bfloat16*)alloc((size_t)262144*2);
  float* u_vec  = (float*)alloc(1024*4);
  float* bc_vec = (float*)alloc(1024*4);
  float* attf   = (float*)alloc(512*4);
  float* gbiasf = (float*)alloc(512*4);
  float* initwf = (float*)alloc(256*4);
  float* outwf  = (float*)alloc(256*4);
  float* sc     = (float*)alloc(2*4);
  int*   flag   = (int*)alloc(4);
  // total ~23.6 MB

  if(off > ws_size){
    k_fail<<<(out_size + 255)/256, 256, 0, stream>>>(out, out_size);
    return;
  }

  // dtype detect + CSR + prep
  k_detect<<<1, 256, 0, stream>>>(x, flag);
  hipMemsetAsync(deg, 0, (size_t)NN*4, stream);
  hipMemsetAsync(csr_src, 0xFF, (size_t)NE*4, stream);
  k_count<<<NE/256, 256, 0, stream>>>(dstp, deg);
  k_scan<<<1, 256, 0, stream>>>(deg, offp, cursor);
  k_fill<<<NE/256, 256, 0, stream>>>(srcp, dstp, cursor, csr_src);
  k_cvt_x<<<NN, 256, 0, stream>>>(x, flag, P);
  k_prep<<<1024, 256, 0, stream>>>(w_src, w_dst, w_hh, flag, wsrcT, wdstT, whhb);
  k_prep_wc<<<1024, 256, 0, stream>>>(w_ih, mlp_w, flag, Wc);
  k_prep_small<<<4, 256, 0, stream>>>(w_ih, mlp_w, mlp_b, b_ih, b_hh, att, gbias,
                                      init_w, init_b, out_w, out_b, flag,
                                      u_vec, bc_vec, attf, gbiasf, initwf, outwf, sc);

  // GAT layers: Q = P@Wsrc^T (xl); P = P@Wdst^T in-place (xr); fused edge phase -> P
  dim3 g64(313, 4);
  for(int l=0;l<2;l++){
    k_gemm_nt_bf<<<g64, 256, 0, stream>>>(P, wsrcT + l*65536, Q);
    k_gemm_inplace<<<313, 256, 0, stream>>>(P, wdstT + l*65536);
    k_node_fused<<<NN, 256, 0, stream>>>(Q, P, offp, csr_src, attf + l*256, gbiasf + l*256);
  }

  // persistent LSTM decoder: in-register activation, GX in LDS
  k_lstm12<<<1250, 256, 0, stream>>>(P, Wc, whhb, u_vec, bc_vec, initwf, outwf, sc, out);
}

// Round 11
// 2158.161 us; speedup vs baseline: 1.5183x; 1.2588x over previous
//
#include <hip/hip_runtime.h>
#include <hip/hip_bf16.h>

#define NN 20000
#define NE 320000
#define TOUT 12
#define DEGMAX 96
#define SGXP 1028   // sgx row stride (bf16): quads hit disjoint bank groups

typedef __bf16 bf16x8 __attribute__((ext_vector_type(8)));
typedef float float4v __attribute__((ext_vector_type(4)));

#define LD8(p) (*(const bf16x8*)(p))
#define MFMA16(a,b,c) __builtin_amdgcn_mfma_f32_16x16x32_bf16((a),(b),(c),0,0,0)

__device__ __forceinline__ float bf2f(const __hip_bfloat16 v){ return __bfloat162float(v); }
__device__ __forceinline__ __hip_bfloat16 f2bf(float v){ return __float2bfloat16(v); }
__device__ __forceinline__ float sigmoidf_(float x){ return 1.0f/(1.0f + __expf(-x)); }
__device__ __forceinline__ float rdf(const void* p, int i, int f32){
  return f32 ? ((const float*)p)[i] : __bfloat162float(((const __hip_bfloat16*)p)[i]);
}

// ---------------- input dtype detector ----------------
__global__ void k_detect(const void* xraw, int* flag){
  __shared__ int cnt;
  if(threadIdx.x == 0) cnt = 0;
  __syncthreads();
  const unsigned* w = (const unsigned*)xraw;
  int local = 0;
  for(int i = threadIdx.x; i < 4096; i += 256){
    unsigned b = (w[i] >> 8) & 0x7F;
    if(b >= 0x33 && b <= 0x3F) local++;
  }
  atomicAdd(&cnt, local);
  __syncthreads();
  if(threadIdx.x == 0) *flag = (cnt > 2048) ? 0 : 1;   // 1 => fp32 inputs
}

// guard signature: constant 256.0 everywhere (fp32 out)
__global__ void k_fail(float* out, int n){
  int i = blockIdx.x*256 + threadIdx.x;
  if(i < n) out[i] = 256.0f;
}

// ---------------- CSR build ----------------
__global__ void k_count(const int* __restrict__ dst, int* __restrict__ deg){
  int e = blockIdx.x*256 + threadIdx.x;
  if(e < NE){
    unsigned d = (unsigned)dst[e];
    if(d < NN) atomicAdd(&deg[d], 1);
  }
}

__global__ void k_scan(const int* __restrict__ deg, int* __restrict__ offp, int* __restrict__ cursor){
  __shared__ int part[256];
  __shared__ int excl[257];
  const int CH = (NN + 255)/256;
  int tid = threadIdx.x;
  int lo = tid*CH;
  int hi = lo + CH; if(hi > NN) hi = NN;
  int s = 0;
  for(int i=lo;i<hi;i++) s += deg[i];
  part[tid] = s;
  __syncthreads();
  if(tid == 0){
    int run = 0;
    for(int i=0;i<256;i++){ excl[i] = run; run += part[i]; }
    excl[256] = run;
  }
  __syncthreads();
  int run = excl[tid];
  for(int i=lo;i<hi;i++){ offp[i] = run; cursor[i] = run; run += deg[i]; }
  if(tid == 0) offp[NN] = excl[256];
}

__global__ void k_fill(const int* __restrict__ src, const int* __restrict__ dst,
                       int* __restrict__ cursor, int* __restrict__ csr_src){
  int e = blockIdx.x*256 + threadIdx.x;
  if(e >= NE) return;
  unsigned d = (unsigned)dst[e];
  if(d >= NN) return;
  unsigned p = (unsigned)atomicAdd(&cursor[d], 1);
  if(p < NE){
    unsigned sv = (unsigned)src[e];
    csr_src[p] = (sv < NN) ? (int)sv : 0;
  }
}

// ---------------- conversions / weight prep ----------------
__global__ void k_cvt_x(const void* __restrict__ x, const int* __restrict__ flag,
                        __hip_bfloat16* __restrict__ xb){
  int i = blockIdx.x*256 + threadIdx.x;
  int f = *flag;
  if(i < NN*256) xb[i] = f2bf(rdf(x, i, f));
}

__global__ void k_prep(const void* __restrict__ w_src, const void* __restrict__ w_dst,
                       const void* __restrict__ w_hh, const int* __restrict__ flag,
                       __hip_bfloat16* __restrict__ wsrcT, __hip_bfloat16* __restrict__ wdstT,
                       __hip_bfloat16* __restrict__ whhb){
  int tid = blockIdx.x*256 + threadIdx.x;
  int f = *flag;
  if(tid < 131072){
    int l = tid >> 16, r = tid & 65535, o = r >> 8, i = r & 255;
    wsrcT[tid] = f2bf(rdf(w_src, l*65536 + i*256 + o, f));
    wdstT[tid] = f2bf(rdf(w_dst, l*65536 + i*256 + o, f));
  }
  if(tid < 262144) whhb[tid] = f2bf(rdf(w_hh, tid, f));
}

// Wc[g,k] = sum_j Wih[g,j] * mlp_w[j, 1+k]
__global__ void k_prep_wc(const void* __restrict__ wih, const void* __restrict__ mlp_w,
                          const int* __restrict__ flag, __hip_bfloat16* __restrict__ Wc){
  int g = blockIdx.x;
  int k = threadIdx.x;
  int f = *flag;
  float s = 0.f;
  for(int j=0;j<256;j++) s += rdf(wih, g*256+j, f) * rdf(mlp_w, j*257 + 1 + k, f);
  Wc[g*256+k] = f2bf(s);
}

__global__ void k_prep_small(const void* __restrict__ wih, const void* __restrict__ mlp_w,
                             const void* __restrict__ mlp_b,
                             const void* __restrict__ b_ih, const void* __restrict__ b_hh,
                             const void* __restrict__ att, const void* __restrict__ gbias,
                             const void* __restrict__ init_w, const void* __restrict__ init_b,
                             const void* __restrict__ out_w, const void* __restrict__ out_b,
                             const int* __restrict__ flag,
                             float* __restrict__ u, float* __restrict__ bc,
                             float* __restrict__ attf, float* __restrict__ gbiasf,
                             float* __restrict__ initwf, float* __restrict__ outwf,
                             float* __restrict__ sc){
  int g = blockIdx.x*256 + threadIdx.x;
  int f = *flag;
  if(g < 1024){
    float su = 0.f, sb = 0.f;
    for(int j=0;j<256;j++){
      float w = rdf(wih, g*256+j, f);
      su += w * rdf(mlp_w, j*257, f);
      sb += w * rdf(mlp_b, j, f);
    }
    u[g] = su;
    bc[g] = sb + rdf(b_ih, g, f) + rdf(b_hh, g, f);
  }
  if(g < 512){ attf[g] = rdf(att, g, f); gbiasf[g] = rdf(gbias, g, f); }
  if(g < 256){ initwf[g] = rdf(init_w, g, f); outwf[g] = rdf(out_w, g, f); }
  if(g == 0){ sc[0] = rdf(init_b, 0, f); sc[1] = rdf(out_b, 0, f); }
}

// ---------------- NT GEMM (out-of-place): Q[m,n] = sum_k P[m,k]*B[n,k] ----------------
__global__ __launch_bounds__(256) void k_gemm_nt_bf(const __hip_bfloat16* __restrict__ A,
                                                    const __hip_bfloat16* __restrict__ B,
                                                    __hip_bfloat16* __restrict__ Cb){
  int wave = threadIdx.x >> 6;
  int lane = threadIdx.x & 63;
  int l16 = lane & 15, quad = lane >> 4, quad8 = quad*8;
  int mBase = blockIdx.x*64 + wave*16;
  int nBase = blockIdx.y*64;
  int arow = mBase + l16; if(arow >= NN) arow = NN-1;
  const __hip_bfloat16* aptr = A + (size_t)arow*256 + quad8;
  float4v acc[4];
  #pragma unroll
  for(int nt=0;nt<4;nt++){ acc[nt][0]=0.f; acc[nt][1]=0.f; acc[nt][2]=0.f; acc[nt][3]=0.f; }
  for(int k0=0;k0<256;k0+=32){
    bf16x8 a = LD8(aptr + k0);
    #pragma unroll
    for(int nt=0;nt<4;nt++){
      const __hip_bfloat16* bptr = B + (size_t)(nBase + nt*16 + l16)*256 + k0 + quad8;
      acc[nt] = MFMA16(a, LD8(bptr), acc[nt]);
    }
  }
  #pragma unroll
  for(int nt=0;nt<4;nt++){
    int col = nBase + nt*16 + l16;
    #pragma unroll
    for(int r=0;r<4;r++){
      int row = mBase + quad*4 + r;
      if(row < NN) Cb[(size_t)row*256 + col] = f2bf(acc[nt][r]);
    }
  }
}

// ---------------- in-place NT GEMM: P = P@B^T (LDS-staged A; row-exclusive blocks) ----
__global__ __launch_bounds__(256) void k_gemm_inplace(__hip_bfloat16* __restrict__ P,
                                                      const __hip_bfloat16* __restrict__ B){
  __shared__ __hip_bfloat16 sA[64*264];
  int tid = threadIdx.x;
  int mBase = blockIdx.x*64;
  {
    int r = tid >> 2;
    int c0 = (tid & 3)*64;
    int grow = mBase + r; if(grow >= NN) grow = NN-1;
    const __hip_bfloat16* srcp = P + (size_t)grow*256 + c0;
    #pragma unroll
    for(int j=0;j<8;j++) *(bf16x8*)(&sA[r*264 + c0 + j*8]) = LD8(srcp + j*8);
  }
  __syncthreads();
  int w = tid>>6, lane = tid&63, l16 = lane&15, quad = lane>>4, quad8 = quad*8;
  const __hip_bfloat16* arow = &sA[(w*16 + l16)*264 + quad8];
  float4v acc[16];
  #pragma unroll
  for(int nt=0;nt<16;nt++){ acc[nt][0]=0.f; acc[nt][1]=0.f; acc[nt][2]=0.f; acc[nt][3]=0.f; }
  for(int k0=0;k0<256;k0+=32){
    bf16x8 a = *(const bf16x8*)(arow + k0);
    #pragma unroll
    for(int nt=0;nt<16;nt++)
      acc[nt] = MFMA16(a, LD8(B + (size_t)(nt*16+l16)*256 + k0 + quad8), acc[nt]);
  }
  #pragma unroll
  for(int nt=0;nt<16;nt++){
    int col = nt*16 + l16;
    #pragma unroll
    for(int r=0;r<4;r++){
      int row = mBase + w*16 + quad*4 + r;
      if(row < NN) P[(size_t)row*256 + col] = f2bf(acc[nt][r]);
    }
  }
}

// ---------------- fused GAT edge phase: logits+softmax+aggregate+ELU (per node) ------
__global__ __launch_bounds__(256) void k_node_fused(const __hip_bfloat16* __restrict__ Q,
                                                    __hip_bfloat16* __restrict__ P,
                                                    const int* __restrict__ offp,
                                                    const int* __restrict__ csr_src,
                                                    const float* __restrict__ attf,
                                                    const float* __restrict__ gbiasf){
  __shared__ float slog[DEGMAX*4];
  __shared__ int ssrc[DEGMAX];
  int node = blockIdx.x;
  int tid = threadIdx.x;
  int s0 = offp[node], s1 = offp[node+1];
  if(s0 < 0) s0 = 0; if(s0 > NE) s0 = NE;
  if(s1 < s0) s1 = s0; if(s1 > NE) s1 = NE;
  int deg = s1 - s0; if(deg > DEGMAX) deg = DEGMAX;
  if(tid < deg){
    unsigned sv = (unsigned)csr_src[s0 + tid];
    ssrc[tid] = (sv < NN) ? (int)sv : 0;
  }
  __syncthreads();
  int w = tid>>6, lane = tid&63;
  for(int idx=w; idx<deg; idx+=4){
    const __hip_bfloat16* pl = Q + (size_t)ssrc[idx]*256;
    const __hip_bfloat16* pr = P + (size_t)node*256;
    float a[4];
    #pragma unroll
    for(int h=0;h<4;h++){
      float v = bf2f(pl[h*64+lane]) + bf2f(pr[h*64+lane]);
      v = (v > 0.f) ? v : 0.2f*v;
      a[h] = v * attf[h*64+lane];
    }
    #pragma unroll
    for(int h=0;h<4;h++){
      float s = a[h];
      s += __shfl_xor(s, 1, 64);
      s += __shfl_xor(s, 2, 64);
      s += __shfl_xor(s, 4, 64);
      s += __shfl_xor(s, 8, 64);
      s += __shfl_xor(s, 16, 64);
      s += __shfl_xor(s, 32, 64);
      if(lane == 0) slog[idx*4 + h] = s;
    }
  }
  __syncthreads();
  if(tid < 4){
    int h = tid;
    float m = -1e30f;
    for(int i=0;i<deg;i++) m = fmaxf(m, slog[i*4+h]);
    float den = 0.f;
    for(int i=0;i<deg;i++) den += __expf(slog[i*4+h] - m);
    float inv = (den > 0.f) ? 1.f/den : 0.f;
    for(int i=0;i<deg;i++) slog[i*4+h] = __expf(slog[i*4+h] - m)*inv;
  }
  __syncthreads();
  int d = tid, h = d>>6;
  float acc = 0.f;
  for(int i=0;i<deg;i++) acc += slog[i*4+h] * bf2f(Q[(size_t)ssrc[i]*256 + d]);
  acc += gbiasf[d];
  acc = (acc > 0.f) ? acc : (__expf(acc) - 1.f);   // ELU
  P[(size_t)node*256 + d] = f2bf(acc);
}

// ---------------- persistent LSTM: 16 rows/block, all 12 steps in one launch ---------
// Wave w owns cols [w*64,(w+1)*64) for ALL 4 gates (nt = g*4+t) -> in-register
// activation, no gate-exchange LDS. GX in LDS. __launch_bounds__(256,2): ~256-reg
// unified budget (128 arch + 128 acc) -> r10's spills (WRITE=757MB at (256,3)/84
// arch regs) eliminated by construction. 2 blocks/CU, 8 waves/CU.
__global__ __launch_bounds__(256, 2) void k_lstm12(const __hip_bfloat16* __restrict__ ctx,
                                                   const __hip_bfloat16* __restrict__ Wc,
                                                   const __hip_bfloat16* __restrict__ Whh,
                                                   const float* __restrict__ u_vec,
                                                   const float* __restrict__ bc_vec,
                                                   const float* __restrict__ initwf,
                                                   const float* __restrict__ outwf,
                                                   const float* __restrict__ sc,
                                                   float* __restrict__ out){
  __shared__ __hip_bfloat16 sgx[16*SGXP];    // 32.9KB: GX+bc, [row][gatecol]
  __shared__ __hip_bfloat16 sh[16*264];      // h tile (bank-padded)
  __shared__ float spart[256];               // init-reduction scratch
  __shared__ float spartw[64];               // per-wave out-projection partials
  __shared__ float sprev[16];
  int tid = threadIdx.x;
  int mBase = blockIdx.x*16;                 // 1250*16 == NN exactly
  int w = tid>>6, lane = tid&63, l16 = lane&15, quad = lane>>4, quad8 = quad*8;
  // h0 = ctx rows
  {
    int r = tid >> 4, c0 = (tid & 15)*16;
    const __hip_bfloat16* srcp = ctx + (size_t)(mBase + r)*256 + c0;
    *(bf16x8*)(&sh[r*264 + c0])     = LD8(srcp);
    *(bf16x8*)(&sh[r*264 + c0 + 8]) = LD8(srcp + 8);
  }
  __syncthreads();
  // prev0 = ctx @ init_w + init_b
  {
    int r = tid >> 4, c0 = (tid & 15)*16;
    float part = 0.f;
    #pragma unroll
    for(int j=0;j<16;j++) part += bf2f(sh[r*264 + c0 + j]) * initwf[c0 + j];
    spart[tid] = part;
  }
  __syncthreads();
  if(tid < 16){
    float s = 0.f;
    #pragma unroll
    for(int j=0;j<16;j++) s += spart[tid*16 + j];
    sprev[tid] = s + sc[0];
  }
  // per-thread constants
  float ureg[16], owreg[4];
  #pragma unroll
  for(int g=0;g<4;g++)
    #pragma unroll
    for(int t=0;t<4;t++) ureg[g*4+t] = u_vec[g*256 + w*64 + t*16 + l16];
  #pragma unroll
  for(int t=0;t<4;t++) owreg[t] = outwf[w*64 + t*16 + l16];
  float outb = sc[1];
  // GX phase: acc = ctx@Wc^T (this wave's 4-gate 64-col slab), +bc, -> sgx
  {
    float4v acc[16];
    #pragma unroll
    for(int nt=0;nt<16;nt++){ acc[nt][0]=0.f; acc[nt][1]=0.f; acc[nt][2]=0.f; acc[nt][3]=0.f; }
    for(int k0=0;k0<256;k0+=32){
      bf16x8 a = *(const bf16x8*)(&sh[l16*264 + k0 + quad8]);
      #pragma unroll
      for(int nt=0;nt<16;nt++){
        int brow = (nt>>2)*256 + w*64 + (nt&3)*16 + l16;
        acc[nt] = MFMA16(a, LD8(Wc + (size_t)brow*256 + k0 + quad8), acc[nt]);
      }
    }
    #pragma unroll
    for(int nt=0;nt<16;nt++){
      int gc = (nt>>2)*256 + w*64 + (nt&3)*16 + l16;
      float bcv = bc_vec[gc];
      #pragma unroll
      for(int r=0;r<4;r++)
        sgx[(quad*4 + r)*SGXP + gc] = f2bf(acc[nt][r] + bcv);
    }
  }
  __syncthreads();   // sgx + sprev visible
  float creg[16];
  #pragma unroll
  for(int i=0;i<16;i++) creg[i] = 0.f;
  for(int step=0; step<TOUT; step++){
    // (a) gates GEMM: acc[g*4+t] = h @ Whh^T slab
    float4v acc[16];
    #pragma unroll
    for(int nt=0;nt<16;nt++){ acc[nt][0]=0.f; acc[nt][1]=0.f; acc[nt][2]=0.f; acc[nt][3]=0.f; }
    for(int k0=0;k0<256;k0+=32){
      bf16x8 a = *(const bf16x8*)(&sh[l16*264 + k0 + quad8]);
      #pragma unroll
      for(int nt=0;nt<16;nt++){
        int brow = (nt>>2)*256 + w*64 + (nt&3)*16 + l16;
        acc[nt] = MFMA16(a, LD8(Whh + (size_t)brow*256 + k0 + quad8), acc[nt]);
      }
    }
    __syncthreads();   // S1: all sh reads done; sprev (from prev step) visible
    // (b) in-register activation + h write + out-projection partials
    float hsum[4] = {0.f, 0.f, 0.f, 0.f};
    #pragma unroll
    for(int t=0;t<4;t++){
      int col = w*64 + t*16 + l16;
      #pragma unroll
      for(int r=0;r<4;r++){
        int row = quad*4 + r;
        float p = sprev[row];
        float g0 = acc[t][r]      + bf2f(sgx[row*SGXP + col])       + p*ureg[t];
        float g1 = acc[4+t][r]    + bf2f(sgx[row*SGXP + 256 + col]) + p*ureg[4+t];
        float g2 = acc[8+t][r]    + bf2f(sgx[row*SGXP + 512 + col]) + p*ureg[8+t];
        float g3 = acc[12+t][r]   + bf2f(sgx[row*SGXP + 768 + col]) + p*ureg[12+t];
        float iv = sigmoidf_(g0), fv = sigmoidf_(g1);
        float gv = tanhf(g2),     ov = sigmoidf_(g3);
        float cn = fv*creg[t*4+r] + iv*gv;
        creg[t*4+r] = cn;
        float hn = ov * tanhf(cn);
        sh[row*264 + col] = f2bf(hn);
        hsum[r] += hn * owreg[t];
      }
    }
    #pragma unroll
    for(int r=0;r<4;r++){
      hsum[r] += __shfl_xor(hsum[r], 1, 64);
      hsum[r] += __shfl_xor(hsum[r], 2, 64);
      hsum[r] += __shfl_xor(hsum[r], 4, 64);
      hsum[r] += __shfl_xor(hsum[r], 8, 64);
    }
    if(l16 == 0){
      #pragma unroll
      for(int r=0;r<4;r++) spartw[w*16 + quad*4 + r] = hsum[r];
    }
    __syncthreads();   // S2: sh writes + spartw visible
    if(tid < 16){
      float s = spartw[tid] + spartw[16+tid] + spartw[32+tid] + spartw[48+tid] + outb;
      sprev[tid] = s;
      out[(size_t)(mBase + tid)*TOUT + step] = s;
    }
    // next S1 makes sprev visible before next activation
  }
}

// ---------------- launch ----------------
extern "C" void kernel_launch(void* const* d_in, const int* in_sizes, int n_in,
                              void* d_out, int out_size, void* d_ws, size_t ws_size,
                              hipStream_t stream){
  const void* x      = d_in[0];
  const int*  ei     = (const int*)d_in[1];
  const void* w_src  = d_in[2];
  const void* w_dst  = d_in[3];
  const void* att    = d_in[4];
  const void* gbias  = d_in[5];
  const void* mlp_w  = d_in[6];
  const void* mlp_b  = d_in[7];
  const void* w_ih   = d_in[8];
  const void* w_hh   = d_in[9];
  const void* b_ih   = d_in[10];
  const void* b_hh   = d_in[11];
  const void* init_w = d_in[12];
  const void* init_b = d_in[13];
  const void* out_w  = d_in[14];
  const void* out_b  = d_in[15];
  float* out = (float*)d_out;
  const int* srcp = ei;
  const int* dstp = ei + NE;
  (void)in_sizes; (void)n_in;

  char* ws = (char*)d_ws;
  size_t off = 0;
  auto alloc = [&](size_t bytes)->void*{
    void* p = ws + off;
    off += (bytes + 255) & ~(size_t)255;
    return p;
  };
  __hip_bfloat16* P = (__hip_bfloat16*)alloc((size_t)NN*256*2);  // x -> xr -> layer out -> ctx
  __hip_bfloat16* Q = (__hip_bfloat16*)alloc((size_t)NN*256*2);  // xl per layer
  int* deg      = (int*)alloc((size_t)NN*4);
  int* offp     = (int*)alloc((size_t)(NN+1)*4);
  int* cursor   = (int*)alloc((size_t)NN*4);
  int* csr_src  = (int*)alloc((size_t)NE*4);
  __hip_bfloat16* wsrcT = (__hip_bfloat16*)alloc((size_t)131072*2);
  __hip_bfloat16* wdstT = (__hip_bfloat16*)alloc((size_t)131072*2);
  __hip_bfloat16* whhb  = (__hip_bfloat16*)alloc((size_t)262144*2);
  __hip_bfloat16* Wc    = (__hip_bfloat16*)alloc((size_t)262144*2);
  float* u_vec  = (float*)alloc(1024*4);
  float* bc_vec = (float*)alloc(1024*4);
  float* attf   = (float*)alloc(512*4);
  float* gbiasf = (float*)alloc(512*4);
  float* initwf = (float*)alloc(256*4);
  float* outwf  = (float*)alloc(256*4);
  float* sc     = (float*)alloc(2*4);
  int*   flag   = (int*)alloc(4);
  // total ~23.6 MB

  if(off > ws_size){
    k_fail<<<(out_size + 255)/256, 256, 0, stream>>>(out, out_size);
    return;
  }

  // dtype detect + CSR + prep
  k_detect<<<1, 256, 0, stream>>>(x, flag);
  hipMemsetAsync(deg, 0, (size_t)NN*4, stream);
  hipMemsetAsync(csr_src, 0xFF, (size_t)NE*4, stream);
  k_count<<<NE/256, 256, 0, stream>>>(dstp, deg);
  k_scan<<<1, 256, 0, stream>>>(deg, offp, cursor);
  k_fill<<<NE/256, 256, 0, stream>>>(srcp, dstp, cursor, csr_src);
  k_cvt_x<<<NN, 256, 0, stream>>>(x, flag, P);
  k_prep<<<1024, 256, 0, stream>>>(w_src, w_dst, w_hh, flag, wsrcT, wdstT, whhb);
  k_prep_wc<<<1024, 256, 0, stream>>>(w_ih, mlp_w, flag, Wc);
  k_prep_small<<<4, 256, 0, stream>>>(w_ih, mlp_w, mlp_b, b_ih, b_hh, att, gbias,
                                      init_w, init_b, out_w, out_b, flag,
                                      u_vec, bc_vec, attf, gbiasf, initwf, outwf, sc);

  // GAT layers: Q = P@Wsrc^T (xl); P = P@Wdst^T in-place (xr); fused edge phase -> P
  dim3 g64(313, 4);
  for(int l=0;l<2;l++){
    k_gemm_nt_bf<<<g64, 256, 0, stream>>>(P, wsrcT + l*65536, Q);
    k_gemm_inplace<<<313, 256, 0, stream>>>(P, wdstT + l*65536);
    k_node_fused<<<NN, 256, 0, stream>>>(Q, P, offp, csr_src, attf + l*256, gbiasf + l*256);
  }

  // persistent LSTM decoder: in-register activation, GX in LDS, no spills
  k_lstm12<<<1250, 256, 0, stream>>>(P, Wc, whhb, u_vec, bc_vec, initwf, outwf, sc, out);
}